// Round 1
// baseline (1076.899 us; speedup 1.0000x reference)
//
#include <hip/hip_runtime.h>
#include <hip/hip_bf16.h>

#define N 512
#define CS 1024
#define CZ 128
#define H 12
#define HD 16

// ---------------------------------------------------------------------------
// dtype sniff: 1 if buffer holds f32, 0 if bf16. Reads 32 16-bit words.
// bf16 N(0,1): exponent field in ~[117,130]. f32 data read as bf16: half the
// words are mantissa fragments with uniform-random exponent bits -> flagged.
// ---------------------------------------------------------------------------
__device__ int sniff_f32(const unsigned short* p) {
    int bad = 0;
    for (int i = 0; i < 32; ++i) {
        unsigned short u = p[i];
        int e = (u >> 7) & 0xFF;
        if (e == 0xFF || e >= 141 || (e <= 27 && (u & 0x7FFFu) != 0)) bad++;
    }
    return bad > 0;
}

__device__ __forceinline__ float ld(const void* p, int i, int f32) {
    return f32 ? ((const float*)p)[i]
               : __bfloat162float(((const __hip_bfloat16*)p)[i]);
}

// ---------------------------------------------------------------------------
// K1: q/k/v projections. grid (512 rows, 3 col-blocks) x 192 threads.
// q: n*192 + h*16 + d ; k,v same layout.
// ---------------------------------------------------------------------------
__global__ void proj_qkv(const void* s, const void* Wq, const void* bq,
                         const void* Wkv, const void* bkv,
                         float* q, float* k, float* v)
{
    __shared__ float sL[CS];
    __shared__ int flag;
    int t = threadIdx.x;
    int i = blockIdx.x;
    int col = blockIdx.y * 192 + t;     // [0,576)
    if (t == 0) flag = sniff_f32((const unsigned short*)s);
    __syncthreads();
    int f32 = flag;
    for (int idx = t; idx < CS; idx += 192) sL[idx] = ld(s, i * CS + idx, f32);
    __syncthreads();
    const void* W; const void* bv; int c, ldim;
    if (col < 192) { W = Wq;  bv = bq;  c = col;       ldim = 192; }
    else           { W = Wkv; bv = bkv; c = col - 192; ldim = 384; }
    float acc = ld(bv, c, f32);
    for (int kk = 0; kk < CS; ++kk) acc += sL[kk] * ld(W, kk * ldim + c, f32);
    if (col < 192) q[i * 192 + col] = acc;
    else {
        int cc = col - 192, h = cc >> 5, t2 = cc & 31;
        if (t2 < 16) k[i * 192 + h * 16 + t2] = acc;
        else         v[i * 192 + h * 16 + (t2 - 16)] = acc;
    }
}

// ---------------------------------------------------------------------------
// K2: point projections + rotation fused. grid 512 x 576 threads.
// Raw cols: qp_raw [0,144) (x|y|z blocks of 48), kvp_raw [144,576) (x|y|z of 144).
// Outputs: qp/kp n*144 + h*12 + p*3 + c ; vp n*288 + h*24 + p*3 + c (global frame)
// ---------------------------------------------------------------------------
__global__ void proj_pts(const void* s, const void* Wqp, const void* bqp,
                         const void* Wkvp, const void* bkvp,
                         const void* rot, const void* trans,
                         float* qp, float* kp, float* vp)
{
    __shared__ float sL[CS];
    __shared__ float rawL[576];
    __shared__ float R[9], T[3];
    __shared__ int flag;
    int t = threadIdx.x;     // 576
    int i = blockIdx.x;
    if (t == 0) flag = sniff_f32((const unsigned short*)s);
    __syncthreads();
    int f32 = flag;
    for (int idx = t; idx < CS; idx += 576) sL[idx] = ld(s, i * CS + idx, f32);
    if (t < 9) R[t] = ld(rot, i * 9 + t, f32);
    if (t >= 16 && t < 19) T[t - 16] = ld(trans, i * 3 + (t - 16), f32);
    __syncthreads();
    const void* W; const void* bv; int c, ldim;
    if (t < 144) { W = Wqp;  bv = bqp;  c = t;       ldim = 144; }
    else         { W = Wkvp; bv = bkvp; c = t - 144; ldim = 432; }
    float acc = ld(bv, c, f32);
    for (int kk = 0; kk < CS; ++kk) acc += sL[kk] * ld(W, kk * ldim + c, f32);
    rawL[t] = acc;
    __syncthreads();
    if (t < 192) {
        float x, y, zc;
        if (t < 48) { x = rawL[t];        y = rawL[48 + t];   zc = rawL[96 + t]; }
        else { int pk = t - 48;
               x = rawL[144 + pk]; y = rawL[288 + pk]; zc = rawL[432 + pk]; }
        float rx = R[0]*x + R[1]*y + R[2]*zc + T[0];
        float ry = R[3]*x + R[4]*y + R[5]*zc + T[1];
        float rz = R[6]*x + R[7]*y + R[8]*zc + T[2];
        if (t < 48) {
            int h = t >> 2, pp = t & 3, b = i * 144 + h * 12 + pp * 3;
            qp[b] = rx; qp[b + 1] = ry; qp[b + 2] = rz;
        } else {
            int pk = t - 48, h = pk / 12, idx = pk % 12;
            if (idx < 4) { int b = i * 144 + h * 12 + idx * 3;
                           kp[b] = rx; kp[b + 1] = ry; kp[b + 2] = rz; }
            else         { int b = i * 288 + h * 24 + (idx - 4) * 3;
                           vp[b] = rx; vp[b + 1] = ry; vp[b + 2] = rz; }
        }
    }
}

// ---------------------------------------------------------------------------
// K3: fused bias + logits + softmax + (o, o_pt, o_pair) per query row i.
// grid 512 x 512 threads. att lives only in LDS (24KB). No bias/att in ws.
// cat layout: o(0..191) x(192..287) y(288..383) z(384..479) norm(480..575) pair(576..2111)
// ---------------------------------------------------------------------------
__global__ void attn_fused(const float* q, const float* k, const float* v,
                           const float* qp, const float* kp, const float* vp,
                           const void* z, const void* Wb, const void* bb,
                           const void* head_w, const void* mask,
                           const void* rot, const void* trans, const void* s,
                           float* cat)
{
    __shared__ float attL[H * N];        // 24 KB
    __shared__ float WbL[CZ * H];        // 6 KB
    __shared__ float pairP[4 * H * CZ];  // 24 KB
    __shared__ float qL[192], qpL[144];
    __shared__ float RL[9], TL[3], bbL[H], hwL[H];
    __shared__ float miS;
    __shared__ int flag;
    int t = threadIdx.x;   // 512
    int i = blockIdx.x;
    if (t == 0) flag = sniff_f32((const unsigned short*)s);
    __syncthreads();
    int f32 = flag;
    for (int idx = t; idx < CZ * H; idx += 512) WbL[idx] = ld(Wb, idx, f32);
    if (t < 192) qL[t] = q[i * 192 + t];
    else if (t < 336) qpL[t - 192] = qp[i * 144 + (t - 192)];
    else if (t < 345) RL[t - 336] = ld(rot, i * 9 + (t - 336), f32);
    else if (t < 348) TL[t - 345] = ld(trans, i * 3 + (t - 345), f32);
    else if (t < 360) bbL[t - 348] = ld(bb, t - 348, f32);
    else if (t < 372) {
        float x = ld(head_w, t - 360, f32);
        float sp = (x > 20.f) ? x : log1pf(expf(x));
        hwL[t - 360] = sp * 0.13608276348795434f;   // softplus * sqrt(1/54)
    }
    else if (t == 372) miS = ld(mask, i, f32);
    __syncthreads();

    // ---- Phase B: logits for all heads, thread = key index j ----
    {
        int j = t;
        float bj[H];
        #pragma unroll
        for (int h = 0; h < H; ++h) bj[h] = bbL[h];
        int zbase = (i * N + j) * CZ;
        for (int c = 0; c < CZ; ++c) {
            float zc = ld(z, zbase + c, f32);
            #pragma unroll
            for (int h = 0; h < H; ++h) bj[h] += zc * WbL[c * H + h];
        }
        float mj = ld(mask, j, f32);
        float mterm = 100000.0f * (miS * mj - 1.0f);
        for (int h = 0; h < H; ++h) {
            float qk = 0.f;
            #pragma unroll
            for (int d = 0; d < HD; ++d) qk += qL[h * 16 + d] * k[j * 192 + h * 16 + d];
            float pt = 0.f;
            int kb = j * 144 + h * 12;
            #pragma unroll
            for (int p = 0; p < 4; ++p) {
                float dx = qpL[h * 12 + p * 3 + 0] - kp[kb + p * 3 + 0];
                float dy = qpL[h * 12 + p * 3 + 1] - kp[kb + p * 3 + 1];
                float dz = qpL[h * 12 + p * 3 + 2] - kp[kb + p * 3 + 2];
                pt += dx * dx + dy * dy + dz * dz;
            }
            attL[h * N + j] = qk * 0.14433756729740643f     // sqrt(1/48)
                            + 0.5773502691896258f * bj[h]   // sqrt(1/3)
                            - 0.5f * hwL[h] * pt + mterm;
        }
    }
    __syncthreads();

    // ---- Phase C: softmax per head (one wave per head) ----
    {
        int w = t >> 6, l = t & 63;
        for (int h = w; h < H; h += 8) {
            float av[8];
            #pragma unroll
            for (int kk = 0; kk < 8; ++kk) av[kk] = attL[h * N + kk * 64 + l];
            float m = av[0];
            #pragma unroll
            for (int kk = 1; kk < 8; ++kk) m = fmaxf(m, av[kk]);
            for (int off = 1; off < 64; off <<= 1) m = fmaxf(m, __shfl_xor(m, off));
            float ssum = 0.f;
            #pragma unroll
            for (int kk = 0; kk < 8; ++kk) { av[kk] = __expf(av[kk] - m); ssum += av[kk]; }
            for (int off = 1; off < 64; off <<= 1) ssum += __shfl_xor(ssum, off);
            float inv = 1.0f / ssum;
            #pragma unroll
            for (int kk = 0; kk < 8; ++kk) attL[h * N + kk * 64 + l] = av[kk] * inv;
        }
    }
    __syncthreads();

    // ---- Phase D1: o = a@v (192 thr), o_pt + inv-frame + norm (96 thr) ----
    if (t < 192) {
        int h = t >> 4, d = t & 15;
        float acc = 0.f;
        for (int j = 0; j < N; ++j) acc += attL[h * N + j] * v[j * 192 + h * 16 + d];
        cat[i * 2112 + t] = acc;
    } else if (t < 288) {
        int hp = t - 192, h = hp >> 3, p = hp & 7;
        float ax = 0, ay = 0, az = 0;
        for (int j = 0; j < N; ++j) {
            float a_ = attL[h * N + j];
            int b2 = j * 288 + h * 24 + p * 3;
            ax += a_ * vp[b2]; ay += a_ * vp[b2 + 1]; az += a_ * vp[b2 + 2];
        }
        float gx = ax - TL[0], gy = ay - TL[1], gz = az - TL[2];
        float lx = RL[0]*gx + RL[3]*gy + RL[6]*gz;   // R^T
        float ly = RL[1]*gx + RL[4]*gy + RL[7]*gz;
        float lz = RL[2]*gx + RL[5]*gy + RL[8]*gz;
        float nrm = sqrtf(lx*lx + ly*ly + lz*lz + 1e-8f);
        cat[i * 2112 + 192 + hp] = lx;
        cat[i * 2112 + 288 + hp] = ly;
        cat[i * 2112 + 384 + hp] = lz;
        cat[i * 2112 + 480 + hp] = nrm;
    }

    // ---- Phase D2: o_pair = a @ z[i]  (all 512 threads, 4 j-quarters) ----
    {
        int quarter = t >> 7, c = t & 127;
        float pacc[H];
        #pragma unroll
        for (int h = 0; h < H; ++h) pacc[h] = 0.f;
        int j0 = quarter * 128;
        for (int j = j0; j < j0 + 128; ++j) {
            float zc = ld(z, (i * N + j) * CZ + c, f32);
            #pragma unroll
            for (int h = 0; h < H; ++h) pacc[h] += attL[h * N + j] * zc;
        }
        #pragma unroll
        for (int h = 0; h < H; ++h) pairP[quarter * (H * CZ) + h * CZ + c] = pacc[h];
    }
    __syncthreads();
    for (int idx = t; idx < H * CZ; idx += 512)
        cat[i * 2112 + 576 + idx] =
            pairP[idx] + pairP[1536 + idx] + pairP[3072 + idx] + pairP[4608 + idx];
}

// ---------------------------------------------------------------------------
// K4: out = cat @ Wout + bout, row-blocked.
// block = 8 rows x 256 cols; grid (4 col-blocks, 64 row-groups) = 256 blocks
// (1 block/CU). cat rows staged in LDS (fp32 workspace -> no dtype branch);
// each Wout value is loaded ONCE per block and FMA'd into 8 row accumulators.
// cat LDS reads are wave-uniform ds_read_b128 broadcasts (conflict-free).
// Wout L2 traffic: 4.4 GB -> 0.55 GB; dtype branch hoisted out of K-loop.
// ---------------------------------------------------------------------------
#define FG_BM 8
__global__ void final_gemm(const float* cat, const void* Wout, const void* bout,
                           void* out, const void* s)
{
    __shared__ float catL[FG_BM * 2112];   // 66 KB
    __shared__ int flag;
    int t = threadIdx.x;                   // 256
    int r0 = blockIdx.y * FG_BM;           // first row of this group
    int c = blockIdx.x * 256 + t;          // output column
    if (t == 0) flag = sniff_f32((const unsigned short*)s);
    __syncthreads();
    int f32 = flag;
    for (int idx = t; idx < FG_BM * 2112; idx += 256)
        catL[idx] = cat[r0 * 2112 + idx];
    __syncthreads();

    float acc[FG_BM];
    float bv = ld(bout, c, f32);
    #pragma unroll
    for (int r = 0; r < FG_BM; ++r) acc[r] = bv;

    if (f32) {
        const float* wp = (const float*)Wout + c;
        #pragma unroll 4
        for (int g = 0; g < 2112 / 4; ++g) {
            float w0 = wp[0 * CS];
            float w1 = wp[1 * CS];
            float w2 = wp[2 * CS];
            float w3 = wp[3 * CS];
            wp += 4 * CS;
            #pragma unroll
            for (int r = 0; r < FG_BM; ++r) {
                float4 cv = *(const float4*)&catL[r * 2112 + 4 * g];
                acc[r] += cv.x * w0 + cv.y * w1 + cv.z * w2 + cv.w * w3;
            }
        }
    } else {
        const unsigned short* wp = (const unsigned short*)Wout + c;
        #pragma unroll 4
        for (int g = 0; g < 2112 / 4; ++g) {
            float w0 = __bfloat162float(*(const __hip_bfloat16*)&wp[0 * CS]);
            float w1 = __bfloat162float(*(const __hip_bfloat16*)&wp[1 * CS]);
            float w2 = __bfloat162float(*(const __hip_bfloat16*)&wp[2 * CS]);
            float w3 = __bfloat162float(*(const __hip_bfloat16*)&wp[3 * CS]);
            wp += 4 * CS;
            #pragma unroll
            for (int r = 0; r < FG_BM; ++r) {
                float4 cv = *(const float4*)&catL[r * 2112 + 4 * g];
                acc[r] += cv.x * w0 + cv.y * w1 + cv.z * w2 + cv.w * w3;
            }
        }
    }

    if (f32) {
        float* o = (float*)out;
        #pragma unroll
        for (int r = 0; r < FG_BM; ++r) o[(r0 + r) * CS + c] = acc[r];
    } else {
        __hip_bfloat16* o = (__hip_bfloat16*)out;
        #pragma unroll
        for (int r = 0; r < FG_BM; ++r) o[(r0 + r) * CS + c] = __float2bfloat16(acc[r]);
    }
}

extern "C" void kernel_launch(void* const* d_in, const int* in_sizes, int n_in,
                              void* d_out, int out_size, void* d_ws, size_t ws_size,
                              hipStream_t stream)
{
    const void* s      = d_in[0];
    const void* z      = d_in[1];
    const void* rot    = d_in[2];
    const void* trans  = d_in[3];
    const void* mask   = d_in[4];
    const void* Wq     = d_in[5];  const void* bq   = d_in[6];
    const void* Wkv    = d_in[7];  const void* bkv  = d_in[8];
    const void* Wqp    = d_in[9];  const void* bqp  = d_in[10];
    const void* Wkvp   = d_in[11]; const void* bkvp = d_in[12];
    const void* Wb     = d_in[13]; const void* bb   = d_in[14];
    const void* head_w = d_in[15];
    const void* Wout   = d_in[16]; const void* bout = d_in[17];

    float* w   = (float*)d_ws;          // total 1,671,168 floats = 6.4 MB
    float* q   = w;                     // 512*192
    float* k   = q  + 98304;
    float* v   = k  + 98304;
    float* qp  = v  + 98304;            // 512*144
    float* kp  = qp + 73728;
    float* vp  = kp + 73728;            // 512*288
    float* cat = vp + 147456;           // 512*2112
    (void)ws_size; (void)in_sizes; (void)n_in; (void)out_size;

    proj_qkv  <<<dim3(512, 3), 192, 0, stream>>>(s, Wq, bq, Wkv, bkv, q, k, v);
    proj_pts  <<<512, 576, 0, stream>>>(s, Wqp, bqp, Wkvp, bkvp, rot, trans, qp, kp, vp);
    attn_fused<<<512, 512, 0, stream>>>(q, k, v, qp, kp, vp, z, Wb, bb, head_w, mask,
                                        rot, trans, s, cat);
    final_gemm<<<dim3(4, 64), 256, 0, stream>>>(cat, Wout, bout, d_out, s);
}

// Round 3
// 787.070 us; speedup vs baseline: 1.3682x; 1.3682x over previous
//
#include <hip/hip_runtime.h>
#include <hip/hip_bf16.h>

#define N 512
#define CS 1024
#define CZ 128
#define H 12
#define HD 16

// ---------------------------------------------------------------------------
// dtype sniff: 1 if buffer holds f32, 0 if bf16. Reads 32 16-bit words.
// ---------------------------------------------------------------------------
__device__ int sniff_f32(const unsigned short* p) {
    int bad = 0;
    for (int i = 0; i < 32; ++i) {
        unsigned short u = p[i];
        int e = (u >> 7) & 0xFF;
        if (e == 0xFF || e >= 141 || (e <= 27 && (u & 0x7FFFu) != 0)) bad++;
    }
    return bad > 0;
}

__device__ __forceinline__ float ld(const void* p, int i, int f32) {
    return f32 ? ((const float*)p)[i]
               : __bfloat162float(((const __hip_bfloat16*)p)[i]);
}

// ---------------------------------------------------------------------------
// K1: q/k/v projections. grid (512 rows, 3 col-blocks) x 192 threads.
// ---------------------------------------------------------------------------
__global__ void proj_qkv(const void* s, const void* Wq, const void* bq,
                         const void* Wkv, const void* bkv,
                         float* q, float* k, float* v)
{
    __shared__ float sL[CS];
    __shared__ int flag;
    int t = threadIdx.x;
    int i = blockIdx.x;
    int col = blockIdx.y * 192 + t;     // [0,576)
    if (t == 0) flag = sniff_f32((const unsigned short*)s);
    __syncthreads();
    int f32 = flag;
    for (int idx = t; idx < CS; idx += 192) sL[idx] = ld(s, i * CS + idx, f32);
    __syncthreads();
    const void* W; const void* bv; int c, ldim;
    if (col < 192) { W = Wq;  bv = bq;  c = col;       ldim = 192; }
    else           { W = Wkv; bv = bkv; c = col - 192; ldim = 384; }
    float acc = ld(bv, c, f32);
    for (int kk = 0; kk < CS; ++kk) acc += sL[kk] * ld(W, kk * ldim + c, f32);
    if (col < 192) q[i * 192 + col] = acc;
    else {
        int cc = col - 192, h = cc >> 5, t2 = cc & 31;
        if (t2 < 16) k[i * 192 + h * 16 + t2] = acc;
        else         v[i * 192 + h * 16 + (t2 - 16)] = acc;
    }
}

// ---------------------------------------------------------------------------
// K2: point projections + rotation fused. grid 512 x 576 threads.
// ---------------------------------------------------------------------------
__global__ void proj_pts(const void* s, const void* Wqp, const void* bqp,
                         const void* Wkvp, const void* bkvp,
                         const void* rot, const void* trans,
                         float* qp, float* kp, float* vp)
{
    __shared__ float sL[CS];
    __shared__ float rawL[576];
    __shared__ float R[9], T[3];
    __shared__ int flag;
    int t = threadIdx.x;     // 576
    int i = blockIdx.x;
    if (t == 0) flag = sniff_f32((const unsigned short*)s);
    __syncthreads();
    int f32 = flag;
    for (int idx = t; idx < CS; idx += 576) sL[idx] = ld(s, i * CS + idx, f32);
    if (t < 9) R[t] = ld(rot, i * 9 + t, f32);
    if (t >= 16 && t < 19) T[t - 16] = ld(trans, i * 3 + (t - 16), f32);
    __syncthreads();
    const void* W; const void* bv; int c, ldim;
    if (t < 144) { W = Wqp;  bv = bqp;  c = t;       ldim = 144; }
    else         { W = Wkvp; bv = bkvp; c = t - 144; ldim = 432; }
    float acc = ld(bv, c, f32);
    for (int kk = 0; kk < CS; ++kk) acc += sL[kk] * ld(W, kk * ldim + c, f32);
    rawL[t] = acc;
    __syncthreads();
    if (t < 192) {
        float x, y, zc;
        if (t < 48) { x = rawL[t];        y = rawL[48 + t];   zc = rawL[96 + t]; }
        else { int pk = t - 48;
               x = rawL[144 + pk]; y = rawL[288 + pk]; zc = rawL[432 + pk]; }
        float rx = R[0]*x + R[1]*y + R[2]*zc + T[0];
        float ry = R[3]*x + R[4]*y + R[5]*zc + T[1];
        float rz = R[6]*x + R[7]*y + R[8]*zc + T[2];
        if (t < 48) {
            int h = t >> 2, pp = t & 3, b = i * 144 + h * 12 + pp * 3;
            qp[b] = rx; qp[b + 1] = ry; qp[b + 2] = rz;
        } else {
            int pk = t - 48, h = pk / 12, idx = pk % 12;
            if (idx < 4) { int b = i * 144 + h * 12 + idx * 3;
                           kp[b] = rx; kp[b + 1] = ry; kp[b + 2] = rz; }
            else         { int b = i * 288 + h * 24 + (idx - 4) * 3;
                           vp[b] = rx; vp[b + 1] = ry; vp[b + 2] = rz; }
        }
    }
}

// ---------------------------------------------------------------------------
// K3: fused bias + logits + softmax + (o, o_pt, o_pair) per query row i.
// ---------------------------------------------------------------------------
__global__ void attn_fused(const float* q, const float* k, const float* v,
                           const float* qp, const float* kp, const float* vp,
                           const void* z, const void* Wb, const void* bb,
                           const void* head_w, const void* mask,
                           const void* rot, const void* trans, const void* s,
                           float* cat)
{
    __shared__ float attL[H * N];        // 24 KB
    __shared__ float WbL[CZ * H];        // 6 KB
    __shared__ float pairP[4 * H * CZ];  // 24 KB
    __shared__ float qL[192], qpL[144];
    __shared__ float RL[9], TL[3], bbL[H], hwL[H];
    __shared__ float miS;
    __shared__ int flag;
    int t = threadIdx.x;   // 512
    int i = blockIdx.x;
    if (t == 0) flag = sniff_f32((const unsigned short*)s);
    __syncthreads();
    int f32 = flag;
    for (int idx = t; idx < CZ * H; idx += 512) WbL[idx] = ld(Wb, idx, f32);
    if (t < 192) qL[t] = q[i * 192 + t];
    else if (t < 336) qpL[t - 192] = qp[i * 144 + (t - 192)];
    else if (t < 345) RL[t - 336] = ld(rot, i * 9 + (t - 336), f32);
    else if (t < 348) TL[t - 345] = ld(trans, i * 3 + (t - 345), f32);
    else if (t < 360) bbL[t - 348] = ld(bb, t - 348, f32);
    else if (t < 372) {
        float x = ld(head_w, t - 360, f32);
        float sp = (x > 20.f) ? x : log1pf(expf(x));
        hwL[t - 360] = sp * 0.13608276348795434f;   // softplus * sqrt(1/54)
    }
    else if (t == 372) miS = ld(mask, i, f32);
    __syncthreads();

    // ---- Phase B: logits for all heads, thread = key index j ----
    {
        int j = t;
        float bj[H];
        #pragma unroll
        for (int h = 0; h < H; ++h) bj[h] = bbL[h];
        int zbase = (i * N + j) * CZ;
        for (int c = 0; c < CZ; ++c) {
            float zc = ld(z, zbase + c, f32);
            #pragma unroll
            for (int h = 0; h < H; ++h) bj[h] += zc * WbL[c * H + h];
        }
        float mj = ld(mask, j, f32);
        float mterm = 100000.0f * (miS * mj - 1.0f);
        for (int h = 0; h < H; ++h) {
            float qk = 0.f;
            #pragma unroll
            for (int d = 0; d < HD; ++d) qk += qL[h * 16 + d] * k[j * 192 + h * 16 + d];
            float pt = 0.f;
            int kb = j * 144 + h * 12;
            #pragma unroll
            for (int p = 0; p < 4; ++p) {
                float dx = qpL[h * 12 + p * 3 + 0] - kp[kb + p * 3 + 0];
                float dy = qpL[h * 12 + p * 3 + 1] - kp[kb + p * 3 + 1];
                float dz = qpL[h * 12 + p * 3 + 2] - kp[kb + p * 3 + 2];
                pt += dx * dx + dy * dy + dz * dz;
            }
            attL[h * N + j] = qk * 0.14433756729740643f     // sqrt(1/48)
                            + 0.5773502691896258f * bj[h]   // sqrt(1/3)
                            - 0.5f * hwL[h] * pt + mterm;
        }
    }
    __syncthreads();

    // ---- Phase C: softmax per head (one wave per head) ----
    {
        int w = t >> 6, l = t & 63;
        for (int h = w; h < H; h += 8) {
            float av[8];
            #pragma unroll
            for (int kk = 0; kk < 8; ++kk) av[kk] = attL[h * N + kk * 64 + l];
            float m = av[0];
            #pragma unroll
            for (int kk = 1; kk < 8; ++kk) m = fmaxf(m, av[kk]);
            for (int off = 1; off < 64; off <<= 1) m = fmaxf(m, __shfl_xor(m, off));
            float ssum = 0.f;
            #pragma unroll
            for (int kk = 0; kk < 8; ++kk) { av[kk] = __expf(av[kk] - m); ssum += av[kk]; }
            for (int off = 1; off < 64; off <<= 1) ssum += __shfl_xor(ssum, off);
            float inv = 1.0f / ssum;
            #pragma unroll
            for (int kk = 0; kk < 8; ++kk) attL[h * N + kk * 64 + l] = av[kk] * inv;
        }
    }
    __syncthreads();

    // ---- Phase D1: o = a@v (192 thr), o_pt + inv-frame + norm (96 thr) ----
    if (t < 192) {
        int h = t >> 4, d = t & 15;
        float acc = 0.f;
        for (int j = 0; j < N; ++j) acc += attL[h * N + j] * v[j * 192 + h * 16 + d];
        cat[i * 2112 + t] = acc;
    } else if (t < 288) {
        int hp = t - 192, h = hp >> 3, p = hp & 7;
        float ax = 0, ay = 0, az = 0;
        for (int j = 0; j < N; ++j) {
            float a_ = attL[h * N + j];
            int b2 = j * 288 + h * 24 + p * 3;
            ax += a_ * vp[b2]; ay += a_ * vp[b2 + 1]; az += a_ * vp[b2 + 2];
        }
        float gx = ax - TL[0], gy = ay - TL[1], gz = az - TL[2];
        float lx = RL[0]*gx + RL[3]*gy + RL[6]*gz;   // R^T
        float ly = RL[1]*gx + RL[4]*gy + RL[7]*gz;
        float lz = RL[2]*gx + RL[5]*gy + RL[8]*gz;
        float nrm = sqrtf(lx*lx + ly*ly + lz*lz + 1e-8f);
        cat[i * 2112 + 192 + hp] = lx;
        cat[i * 2112 + 288 + hp] = ly;
        cat[i * 2112 + 384 + hp] = lz;
        cat[i * 2112 + 480 + hp] = nrm;
    }

    // ---- Phase D2: o_pair = a @ z[i]  (all 512 threads, 4 j-quarters) ----
    {
        int quarter = t >> 7, c = t & 127;
        float pacc[H];
        #pragma unroll
        for (int h = 0; h < H; ++h) pacc[h] = 0.f;
        int j0 = quarter * 128;
        for (int j = j0; j < j0 + 128; ++j) {
            float zc = ld(z, (i * N + j) * CZ + c, f32);
            #pragma unroll
            for (int h = 0; h < H; ++h) pacc[h] += attL[h * N + j] * zc;
        }
        #pragma unroll
        for (int h = 0; h < H; ++h) pairP[quarter * (H * CZ) + h * CZ + c] = pacc[h];
    }
    __syncthreads();
    for (int idx = t; idx < H * CZ; idx += 512)
        cat[i * 2112 + 576 + idx] =
            pairP[idx] + pairP[1536 + idx] + pairP[3072 + idx] + pairP[4608 + idx];
}

// ---------------------------------------------------------------------------
// K4: out = cat @ Wout + bout via split-precision bf16 MFMA.
// x = hi + lo (hi = bf16(x), lo = bf16(x - hi)); A*B = Ah*Bh + Ah*Bl + Al*Bh
// (residual ~2^-17 rel, below f32 reorder noise).
// Tile 32(M) x 64(N) x 32(K); 256 thr = 4 waves (2x2); wave = 16x32 strip =
// 2 frags of mfma_f32_16x16x32_bf16 x 3 split terms. Grid (16,16)=256 blocks
// = full chip. B staged transposed Bt[n][k], rows padded to 40 bf16 (~2-way
// bank aliasing = free). Frag layouts per verified m89/m92 mapping:
// A: lane row=l&15, k=(l>>4)*8+e contiguous; D: row=(l>>4)*4+r, col=l&15.
// ---------------------------------------------------------------------------
typedef __attribute__((ext_vector_type(8))) short bf16x8;
typedef __attribute__((ext_vector_type(4))) float f32x4;
typedef __attribute__((ext_vector_type(4))) unsigned short u16x4;
typedef __attribute__((ext_vector_type(8))) unsigned short u16x8;

#define FG_LDA 40   // padded row length (bf16 elems) for 32-k tiles

// returns hi bf16 in low 16 bits, lo bf16 in high 16 bits
__device__ __forceinline__ unsigned int split_bf16(float x) {
    __hip_bfloat16 hb = __float2bfloat16(x);
    float hf = __bfloat162float(hb);
    __hip_bfloat16 lb = __float2bfloat16(x - hf);
    unsigned int h = *reinterpret_cast<unsigned short*>(&hb);
    unsigned int l = *reinterpret_cast<unsigned short*>(&lb);
    return h | (l << 16);
}

__global__ void final_gemm(const float* cat, const void* Wout, const void* bout,
                           void* out, const void* s)
{
    __shared__ unsigned short Ah[32][FG_LDA], Al[32][FG_LDA];   // 5 KB
    __shared__ unsigned short Bh[64][FG_LDA], Bl[64][FG_LDA];   // 10 KB
    __shared__ int flag;
    int t = threadIdx.x;               // 256
    int bn = blockIdx.x;               // 16 col tiles of 64
    int bm = blockIdx.y;               // 16 row tiles of 32
    if (t == 0) flag = sniff_f32((const unsigned short*)s);
    __syncthreads();
    int f32 = flag;

    int w  = t >> 6, l = t & 63;
    int wm = w >> 1, wn = w & 1;       // wave tile: rows wm*16, cols wn*32
    int lr = l & 15, lq = l >> 4;      // frag: row/col = lr, k-group = lq*8

    // staging assignments
    int am = t >> 3, aq = t & 7;       // A: row am (0..31), 4 floats at aq*4
    int bc = t >> 2, bq = t & 3;       // B: col bc (0..63), 8 k's at bq*8

    f32x4 acc0 = {0.f, 0.f, 0.f, 0.f};
    f32x4 acc1 = {0.f, 0.f, 0.f, 0.f};

    const float* arow = &cat[(bm * 32 + am) * 2112];

    for (int kt = 0; kt < 2112 / 32; ++kt) {
        // ---- stage A: 32x32 f32 -> hi/lo bf16, contiguous b64 writes ----
        {
            float4 xv = *(const float4*)&arow[kt * 32 + aq * 4];
            unsigned int p0 = split_bf16(xv.x);
            unsigned int p1 = split_bf16(xv.y);
            unsigned int p2 = split_bf16(xv.z);
            unsigned int p3 = split_bf16(xv.w);
            u16x4 hh, ll;
            hh[0] = (unsigned short)p0; ll[0] = (unsigned short)(p0 >> 16);
            hh[1] = (unsigned short)p1; ll[1] = (unsigned short)(p1 >> 16);
            hh[2] = (unsigned short)p2; ll[2] = (unsigned short)(p2 >> 16);
            hh[3] = (unsigned short)p3; ll[3] = (unsigned short)(p3 >> 16);
            *(u16x4*)&Ah[am][aq * 4] = hh;
            *(u16x4*)&Al[am][aq * 4] = ll;
        }
        // ---- stage B transposed: Bt[n][k], contiguous b128 writes ----
        {
            int kbase = kt * 32 + bq * 8;
            u16x8 hh, ll;
            #pragma unroll
            for (int e = 0; e < 8; ++e) {
                float x = ld(Wout, (kbase + e) * CS + bn * 64 + bc, f32);
                unsigned int pe = split_bf16(x);
                hh[e] = (unsigned short)pe;
                ll[e] = (unsigned short)(pe >> 16);
            }
            *(u16x8*)&Bh[bc][bq * 8] = hh;
            *(u16x8*)&Bl[bc][bq * 8] = ll;
        }
        __syncthreads();
        // ---- fragments + MFMA ----
        bf16x8 a_h = *(const bf16x8*)&Ah[wm * 16 + lr][lq * 8];
        bf16x8 a_l = *(const bf16x8*)&Al[wm * 16 + lr][lq * 8];
        bf16x8 b0h = *(const bf16x8*)&Bh[wn * 32 + lr][lq * 8];
        bf16x8 b0l = *(const bf16x8*)&Bl[wn * 32 + lr][lq * 8];
        bf16x8 b1h = *(const bf16x8*)&Bh[wn * 32 + 16 + lr][lq * 8];
        bf16x8 b1l = *(const bf16x8*)&Bl[wn * 32 + 16 + lr][lq * 8];
        acc0 = __builtin_amdgcn_mfma_f32_16x16x32_bf16(a_h, b0h, acc0, 0, 0, 0);
        acc0 = __builtin_amdgcn_mfma_f32_16x16x32_bf16(a_h, b0l, acc0, 0, 0, 0);
        acc0 = __builtin_amdgcn_mfma_f32_16x16x32_bf16(a_l, b0h, acc0, 0, 0, 0);
        acc1 = __builtin_amdgcn_mfma_f32_16x16x32_bf16(a_h, b1h, acc1, 0, 0, 0);
        acc1 = __builtin_amdgcn_mfma_f32_16x16x32_bf16(a_h, b1l, acc1, 0, 0, 0);
        acc1 = __builtin_amdgcn_mfma_f32_16x16x32_bf16(a_l, b1h, acc1, 0, 0, 0);
        __syncthreads();
    }

    // ---- epilogue: D row=(l>>4)*4+r, col=l&15 ----
    int col0 = bn * 64 + wn * 32 + lr;
    int row0 = bm * 32 + wm * 16 + lq * 4;
    float bv0 = ld(bout, col0, f32);
    float bv1 = ld(bout, col0 + 16, f32);
    if (f32) {
        float* o = (float*)out;
        #pragma unroll
        for (int r = 0; r < 4; ++r) {
            o[(row0 + r) * CS + col0]      = acc0[r] + bv0;
            o[(row0 + r) * CS + col0 + 16] = acc1[r] + bv1;
        }
    } else {
        __hip_bfloat16* o = (__hip_bfloat16*)out;
        #pragma unroll
        for (int r = 0; r < 4; ++r) {
            o[(row0 + r) * CS + col0]      = __float2bfloat16(acc0[r] + bv0);
            o[(row0 + r) * CS + col0 + 16] = __float2bfloat16(acc1[r] + bv1);
        }
    }
}

extern "C" void kernel_launch(void* const* d_in, const int* in_sizes, int n_in,
                              void* d_out, int out_size, void* d_ws, size_t ws_size,
                              hipStream_t stream)
{
    const void* s      = d_in[0];
    const void* z      = d_in[1];
    const void* rot    = d_in[2];
    const void* trans  = d_in[3];
    const void* mask   = d_in[4];
    const void* Wq     = d_in[5];  const void* bq   = d_in[6];
    const void* Wkv    = d_in[7];  const void* bkv  = d_in[8];
    const void* Wqp    = d_in[9];  const void* bqp  = d_in[10];
    const void* Wkvp   = d_in[11]; const void* bkvp = d_in[12];
    const void* Wb     = d_in[13]; const void* bb   = d_in[14];
    const void* head_w = d_in[15];
    const void* Wout   = d_in[16]; const void* bout = d_in[17];

    float* w   = (float*)d_ws;          // total 1,671,168 floats = 6.4 MB
    float* q   = w;                     // 512*192
    float* k   = q  + 98304;
    float* v   = k  + 98304;
    float* qp  = v  + 98304;            // 512*144
    float* kp  = qp + 73728;
    float* vp  = kp + 73728;            // 512*288
    float* cat = vp + 147456;           // 512*2112
    (void)ws_size; (void)in_sizes; (void)n_in; (void)out_size;

    proj_qkv  <<<dim3(512, 3), 192, 0, stream>>>(s, Wq, bq, Wkv, bkv, q, k, v);
    proj_pts  <<<512, 576, 0, stream>>>(s, Wqp, bqp, Wkvp, bkvp, rot, trans, qp, kp, vp);
    attn_fused<<<512, 512, 0, stream>>>(q, k, v, qp, kp, vp, z, Wb, bb, head_w, mask,
                                        rot, trans, s, cat);
    final_gemm<<<dim3(16, 16), 256, 0, stream>>>(cat, Wout, bout, d_out, s);
}

// Round 5
// 510.609 us; speedup vs baseline: 2.1090x; 1.5414x over previous
//
#include <hip/hip_runtime.h>
#include <hip/hip_bf16.h>

#define N 512
#define CS 1024
#define CZ 128
#define H 12
#define HD 16

// ---------------------------------------------------------------------------
// dtype sniff: 1 if buffer holds f32, 0 if bf16. Reads 32 16-bit words.
// ---------------------------------------------------------------------------
__device__ int sniff_f32(const unsigned short* p) {
    int bad = 0;
    for (int i = 0; i < 32; ++i) {
        unsigned short u = p[i];
        int e = (u >> 7) & 0xFF;
        if (e == 0xFF || e >= 141 || (e <= 27 && (u & 0x7FFFu) != 0)) bad++;
    }
    return bad > 0;
}

__device__ __forceinline__ float ld(const void* p, int i, int f32) {
    return f32 ? ((const float*)p)[i]
               : __bfloat162float(((const __hip_bfloat16*)p)[i]);
}

__device__ __forceinline__ float bfu(unsigned short u) {
    return __bfloat162float(*(const __hip_bfloat16*)&u);
}

// ---------------------------------------------------------------------------
// split-precision helpers for f32-accurate bf16 MFMA:
// x = hi + lo (hi = bf16(x), lo = bf16(x-hi)); A*B = Ah*Bh + Ah*Bl + Al*Bh.
// ---------------------------------------------------------------------------
typedef __attribute__((ext_vector_type(8))) short bf16x8;
typedef __attribute__((ext_vector_type(4))) float f32x4;
typedef __attribute__((ext_vector_type(4))) unsigned short u16x4;
typedef __attribute__((ext_vector_type(8))) unsigned short u16x8;

#define FG_LDA 40   // padded row length (bf16 elems) for 32-k tiles

// returns hi bf16 in low 16 bits, lo bf16 in high 16 bits
__device__ __forceinline__ unsigned int split_bf16(float x) {
    __hip_bfloat16 hb = __float2bfloat16(x);
    float hf = __bfloat162float(hb);
    __hip_bfloat16 lb = __float2bfloat16(x - hf);
    unsigned int h = *reinterpret_cast<unsigned short*>(&hb);
    unsigned int l = *reinterpret_cast<unsigned short*>(&lb);
    return h | (l << 16);
}

// ---------------------------------------------------------------------------
// K1: proj_gemm — rawP = s @ [Wq | Wkv | Wqp | Wkvp]  (512 x 1152, K=1024)
// split-bf16 MFMA, tile 32x64x32, 256 thr = 4 waves (2x2), grid (18,16).
// rawP layout: row-major, 1152 cols: [0,192) Wq, [192,576) Wkv,
// [576,720) Wqp, [720,1152) Wkvp. Biases added in proj_post.
// ---------------------------------------------------------------------------
__device__ __forceinline__ void wcat_resolve(int col,
        const void* Wq, const void* Wkv, const void* Wqp, const void* Wkvp,
        const void*& W, int& cc, int& ldim) {
    if (col < 192)      { W = Wq;   cc = col;       ldim = 192; }
    else if (col < 576) { W = Wkv;  cc = col - 192; ldim = 384; }
    else if (col < 720) { W = Wqp;  cc = col - 576; ldim = 144; }
    else                { W = Wkvp; cc = col - 720; ldim = 432; }
}

__global__ void proj_gemm(const void* s,
                          const void* Wq, const void* Wkv,
                          const void* Wqp, const void* Wkvp,
                          float* rawP)
{
    __shared__ unsigned short Ah[32][FG_LDA], Al[32][FG_LDA];
    __shared__ unsigned short Bh[64][FG_LDA], Bl[64][FG_LDA];
    __shared__ int flag;
    int t = threadIdx.x;               // 256
    int bn = blockIdx.x;               // 18 col tiles of 64
    int bm = blockIdx.y;               // 16 row tiles of 32
    if (t == 0) flag = sniff_f32((const unsigned short*)s);
    __syncthreads();
    int f32 = flag;

    int w  = t >> 6, l = t & 63;
    int wm = w >> 1, wn = w & 1;
    int lr = l & 15, lq = l >> 4;

    int am = t >> 3, aq = t & 7;       // A: row am, 4 vals at aq*4
    int bc = t >> 2, bq = t & 3;       // B: col bc, 8 k's at bq*8

    // resolve B source once (column fixed per thread)
    const void* Wsrc; int wcc, wld;
    wcat_resolve(bn * 64 + bc, Wq, Wkv, Wqp, Wkvp, Wsrc, wcc, wld);

    f32x4 acc0 = {0.f, 0.f, 0.f, 0.f};
    f32x4 acc1 = {0.f, 0.f, 0.f, 0.f};

    int arowbase = (bm * 32 + am) * CS;

    for (int kt = 0; kt < CS / 32; ++kt) {
        // ---- stage A (s, dtype-generic) ----
        {
            int base = arowbase + kt * 32 + aq * 4;
            u16x4 hh, ll;
            #pragma unroll
            for (int e = 0; e < 4; ++e) {
                unsigned int pe = split_bf16(ld(s, base + e, f32));
                hh[e] = (unsigned short)pe; ll[e] = (unsigned short)(pe >> 16);
            }
            *(u16x4*)&Ah[am][aq * 4] = hh;
            *(u16x4*)&Al[am][aq * 4] = ll;
        }
        // ---- stage B transposed ----
        {
            int kbase = kt * 32 + bq * 8;
            u16x8 hh, ll;
            #pragma unroll
            for (int e = 0; e < 8; ++e) {
                unsigned int pe = split_bf16(ld(Wsrc, (kbase + e) * wld + wcc, f32));
                hh[e] = (unsigned short)pe; ll[e] = (unsigned short)(pe >> 16);
            }
            *(u16x8*)&Bh[bc][bq * 8] = hh;
            *(u16x8*)&Bl[bc][bq * 8] = ll;
        }
        __syncthreads();
        bf16x8 a_h = *(const bf16x8*)&Ah[wm * 16 + lr][lq * 8];
        bf16x8 a_l = *(const bf16x8*)&Al[wm * 16 + lr][lq * 8];
        bf16x8 b0h = *(const bf16x8*)&Bh[wn * 32 + lr][lq * 8];
        bf16x8 b0l = *(const bf16x8*)&Bl[wn * 32 + lr][lq * 8];
        bf16x8 b1h = *(const bf16x8*)&Bh[wn * 32 + 16 + lr][lq * 8];
        bf16x8 b1l = *(const bf16x8*)&Bl[wn * 32 + 16 + lr][lq * 8];
        acc0 = __builtin_amdgcn_mfma_f32_16x16x32_bf16(a_h, b0h, acc0, 0, 0, 0);
        acc0 = __builtin_amdgcn_mfma_f32_16x16x32_bf16(a_h, b0l, acc0, 0, 0, 0);
        acc0 = __builtin_amdgcn_mfma_f32_16x16x32_bf16(a_l, b0h, acc0, 0, 0, 0);
        acc1 = __builtin_amdgcn_mfma_f32_16x16x32_bf16(a_h, b1h, acc1, 0, 0, 0);
        acc1 = __builtin_amdgcn_mfma_f32_16x16x32_bf16(a_h, b1l, acc1, 0, 0, 0);
        acc1 = __builtin_amdgcn_mfma_f32_16x16x32_bf16(a_l, b1h, acc1, 0, 0, 0);
        __syncthreads();
    }

    int col0 = bn * 64 + wn * 32 + lr;
    int row0 = bm * 32 + wm * 16 + lq * 4;
    #pragma unroll
    for (int r = 0; r < 4; ++r) {
        rawP[(row0 + r) * 1152 + col0]      = acc0[r];
        rawP[(row0 + r) * 1152 + col0 + 16] = acc1[r];
    }
}

// ---------------------------------------------------------------------------
// K2: proj_post — bias add + q/k/v scatter + point rotation.
// grid 512 x 576 threads.
// ---------------------------------------------------------------------------
__global__ void proj_post(const float* rawP,
                          const void* bq, const void* bkv,
                          const void* bqp, const void* bkvp,
                          const void* rot, const void* trans, const void* s,
                          float* q, float* k, float* v,
                          float* qp, float* kp, float* vp)
{
    __shared__ float rawL[576];
    __shared__ float R[9], T[3];
    __shared__ int flag;
    int t = threadIdx.x;     // 576
    int i = blockIdx.x;
    if (t == 0) flag = sniff_f32((const unsigned short*)s);
    __syncthreads();
    int f32 = flag;

    // qkv scatter
    {
        float val = rawP[i * 1152 + t];
        if (t < 192) q[i * 192 + t] = val + ld(bq, t, f32);
        else {
            int cc = t - 192;
            float vv = val + ld(bkv, cc, f32);
            int h = cc >> 5, t2 = cc & 31;
            if (t2 < 16) k[i * 192 + h * 16 + t2] = vv;
            else         v[i * 192 + h * 16 + (t2 - 16)] = vv;
        }
    }
    // points: bias + stage
    rawL[t] = rawP[i * 1152 + 576 + t]
            + (t < 144 ? ld(bqp, t, f32) : ld(bkvp, t - 144, f32));
    if (t < 9) R[t] = ld(rot, i * 9 + t, f32);
    if (t >= 16 && t < 19) T[t - 16] = ld(trans, i * 3 + (t - 16), f32);
    __syncthreads();
    if (t < 192) {
        float x, y, zc;
        if (t < 48) { x = rawL[t];        y = rawL[48 + t];   zc = rawL[96 + t]; }
        else { int pk = t - 48;
               x = rawL[144 + pk]; y = rawL[288 + pk]; zc = rawL[432 + pk]; }
        float rx = R[0]*x + R[1]*y + R[2]*zc + T[0];
        float ry = R[3]*x + R[4]*y + R[5]*zc + T[1];
        float rz = R[6]*x + R[7]*y + R[8]*zc + T[2];
        if (t < 48) {
            int h = t >> 2, pp = t & 3, b = i * 144 + h * 12 + pp * 3;
            qp[b] = rx; qp[b + 1] = ry; qp[b + 2] = rz;
        } else {
            int pk = t - 48, h = pk / 12, idx = pk % 12;
            if (idx < 4) { int b = i * 144 + h * 12 + idx * 3;
                           kp[b] = rx; kp[b + 1] = ry; kp[b + 2] = rz; }
            else         { int b = i * 288 + h * 24 + (idx - 4) * 3;
                           vp[b] = rx; vp[b + 1] = ry; vp[b + 2] = rz; }
        }
    }
}

// ---------------------------------------------------------------------------
// K3: fused bias + logits + softmax + (o, o_pt, o_pair) per query row i.
// Phase B z/k/kp loads vectorized (dtype branch hoisted out of the loop).
// ---------------------------------------------------------------------------
__global__ void attn_fused(const float* q, const float* k, const float* v,
                           const float* qp, const float* kp, const float* vp,
                           const void* z, const void* Wb, const void* bb,
                           const void* head_w, const void* mask,
                           const void* rot, const void* trans, const void* s,
                           float* cat)
{
    __shared__ float attL[H * N];        // 24 KB
    __shared__ float WbL[CZ * H];        // 6 KB
    __shared__ float pairP[4 * H * CZ];  // 24 KB
    __shared__ float qL[192], qpL[144];
    __shared__ float RL[9], TL[3], bbL[H], hwL[H];
    __shared__ float miS;
    __shared__ int flag;
    int t = threadIdx.x;   // 512
    int i = blockIdx.x;
    if (t == 0) flag = sniff_f32((const unsigned short*)s);
    __syncthreads();
    int f32 = flag;
    for (int idx = t; idx < CZ * H; idx += 512) WbL[idx] = ld(Wb, idx, f32);
    if (t < 192) qL[t] = q[i * 192 + t];
    else if (t < 336) qpL[t - 192] = qp[i * 144 + (t - 192)];
    else if (t < 345) RL[t - 336] = ld(rot, i * 9 + (t - 336), f32);
    else if (t < 348) TL[t - 345] = ld(trans, i * 3 + (t - 345), f32);
    else if (t < 360) bbL[t - 348] = ld(bb, t - 348, f32);
    else if (t < 372) {
        float x = ld(head_w, t - 360, f32);
        float sp = (x > 20.f) ? x : log1pf(expf(x));
        hwL[t - 360] = sp * 0.13608276348795434f;   // softplus * sqrt(1/54)
    }
    else if (t == 372) miS = ld(mask, i, f32);
    __syncthreads();

    // ---- Phase B: logits for all heads, thread = key index j ----
    {
        int j = t;
        float bj[H];
        #pragma unroll
        for (int h = 0; h < H; ++h) bj[h] = bbL[h];
        int zbase = (i * N + j) * CZ;

        if (f32) {
            const float4* zp = (const float4*)((const float*)z + zbase);
            #pragma unroll 4
            for (int c4 = 0; c4 < CZ / 4; ++c4) {
                float4 zv = zp[c4];
                int c0 = c4 * 4;
                #pragma unroll
                for (int h = 0; h < H; ++h)
                    bj[h] += zv.x * WbL[(c0 + 0) * H + h]
                           + zv.y * WbL[(c0 + 1) * H + h]
                           + zv.z * WbL[(c0 + 2) * H + h]
                           + zv.w * WbL[(c0 + 3) * H + h];
            }
        } else {
            const ushort4* zp = (const ushort4*)((const unsigned short*)z + zbase);
            #pragma unroll 4
            for (int c4 = 0; c4 < CZ / 4; ++c4) {
                ushort4 u = zp[c4];
                float zx = bfu(u.x), zy = bfu(u.y), zz = bfu(u.z), zw = bfu(u.w);
                int c0 = c4 * 4;
                #pragma unroll
                for (int h = 0; h < H; ++h)
                    bj[h] += zx * WbL[(c0 + 0) * H + h]
                           + zy * WbL[(c0 + 1) * H + h]
                           + zz * WbL[(c0 + 2) * H + h]
                           + zw * WbL[(c0 + 3) * H + h];
            }
        }

        float mj = ld(mask, j, f32);
        float mterm = 100000.0f * (miS * mj - 1.0f);
        const float4* kj4  = (const float4*)&k[j * 192];
        const float4* kp4  = (const float4*)&kp[j * 144];
        #pragma unroll
        for (int h = 0; h < H; ++h) {
            float4 ka = kj4[h * 4 + 0], kb = kj4[h * 4 + 1];
            float4 kc = kj4[h * 4 + 2], kd = kj4[h * 4 + 3];
            float qk = qL[h*16+ 0]*ka.x + qL[h*16+ 1]*ka.y + qL[h*16+ 2]*ka.z + qL[h*16+ 3]*ka.w
                     + qL[h*16+ 4]*kb.x + qL[h*16+ 5]*kb.y + qL[h*16+ 6]*kb.z + qL[h*16+ 7]*kb.w
                     + qL[h*16+ 8]*kc.x + qL[h*16+ 9]*kc.y + qL[h*16+10]*kc.z + qL[h*16+11]*kc.w
                     + qL[h*16+12]*kd.x + qL[h*16+13]*kd.y + qL[h*16+14]*kd.z + qL[h*16+15]*kd.w;
            float4 p0 = kp4[h * 3 + 0], p1 = kp4[h * 3 + 1], p2 = kp4[h * 3 + 2];
            float dx0 = qpL[h*12+ 0]-p0.x, dy0 = qpL[h*12+ 1]-p0.y, dz0 = qpL[h*12+ 2]-p0.z;
            float dx1 = qpL[h*12+ 3]-p0.w, dy1 = qpL[h*12+ 4]-p1.x, dz1 = qpL[h*12+ 5]-p1.y;
            float dx2 = qpL[h*12+ 6]-p1.z, dy2 = qpL[h*12+ 7]-p1.w, dz2 = qpL[h*12+ 8]-p2.x;
            float dx3 = qpL[h*12+ 9]-p2.y, dy3 = qpL[h*12+10]-p2.z, dz3 = qpL[h*12+11]-p2.w;
            float pt = dx0*dx0 + dy0*dy0 + dz0*dz0
                     + dx1*dx1 + dy1*dy1 + dz1*dz1
                     + dx2*dx2 + dy2*dy2 + dz2*dz2
                     + dx3*dx3 + dy3*dy3 + dz3*dz3;
            attL[h * N + j] = qk * 0.14433756729740643f     // sqrt(1/48)
                            + 0.5773502691896258f * bj[h]   // sqrt(1/3)
                            - 0.5f * hwL[h] * pt + mterm;
        }
    }
    __syncthreads();

    // ---- Phase C: softmax per head (one wave per head) ----
    {
        int w = t >> 6, l = t & 63;
        for (int h = w; h < H; h += 8) {
            float av[8];
            #pragma unroll
            for (int kk = 0; kk < 8; ++kk) av[kk] = attL[h * N + kk * 64 + l];
            float m = av[0];
            #pragma unroll
            for (int kk = 1; kk < 8; ++kk) m = fmaxf(m, av[kk]);
            for (int off = 1; off < 64; off <<= 1) m = fmaxf(m, __shfl_xor(m, off));
            float ssum = 0.f;
            #pragma unroll
            for (int kk = 0; kk < 8; ++kk) { av[kk] = __expf(av[kk] - m); ssum += av[kk]; }
            for (int off = 1; off < 64; off <<= 1) ssum += __shfl_xor(ssum, off);
            float inv = 1.0f / ssum;
            #pragma unroll
            for (int kk = 0; kk < 8; ++kk) attL[h * N + kk * 64 + l] = av[kk] * inv;
        }
    }
    __syncthreads();

    // ---- Phase D1: o = a@v (192 thr), o_pt + inv-frame + norm (96 thr) ----
    if (t < 192) {
        int h = t >> 4, d = t & 15;
        float acc = 0.f;
        for (int j = 0; j < N; ++j) acc += attL[h * N + j] * v[j * 192 + h * 16 + d];
        cat[i * 2112 + t] = acc;
    } else if (t < 288) {
        int hp = t - 192, h = hp >> 3, p = hp & 7;
        float ax = 0, ay = 0, az = 0;
        for (int j = 0; j < N; ++j) {
            float a_ = attL[h * N + j];
            int b2 = j * 288 + h * 24 + p * 3;
            ax += a_ * vp[b2]; ay += a_ * vp[b2 + 1]; az += a_ * vp[b2 + 2];
        }
        float gx = ax - TL[0], gy = ay - TL[1], gz = az - TL[2];
        float lx = RL[0]*gx + RL[3]*gy + RL[6]*gz;   // R^T
        float ly = RL[1]*gx + RL[4]*gy + RL[7]*gz;
        float lz = RL[2]*gx + RL[5]*gy + RL[8]*gz;
        float nrm = sqrtf(lx*lx + ly*ly + lz*lz + 1e-8f);
        cat[i * 2112 + 192 + hp] = lx;
        cat[i * 2112 + 288 + hp] = ly;
        cat[i * 2112 + 384 + hp] = lz;
        cat[i * 2112 + 480 + hp] = nrm;
    }

    // ---- Phase D2: o_pair = a @ z[i]  (all 512 threads, 4 j-quarters) ----
    {
        int quarter = t >> 7, c = t & 127;
        float pacc[H];
        #pragma unroll
        for (int h = 0; h < H; ++h) pacc[h] = 0.f;
        int j0 = quarter * 128;
        for (int j = j0; j < j0 + 128; ++j) {
            float zc = ld(z, (i * N + j) * CZ + c, f32);
            #pragma unroll
            for (int h = 0; h < H; ++h) pacc[h] += attL[h * N + j] * zc;
        }
        #pragma unroll
        for (int h = 0; h < H; ++h) pairP[quarter * (H * CZ) + h * CZ + c] = pacc[h];
    }
    __syncthreads();
    for (int idx = t; idx < H * CZ; idx += 512)
        cat[i * 2112 + 576 + idx] =
            pairP[idx] + pairP[1536 + idx] + pairP[3072 + idx] + pairP[4608 + idx];
}

// ---------------------------------------------------------------------------
// K4: out = cat @ Wout + bout via split-precision bf16 MFMA (unchanged).
// ---------------------------------------------------------------------------
__global__ void final_gemm(const float* cat, const void* Wout, const void* bout,
                           void* out, const void* s)
{
    __shared__ unsigned short Ah[32][FG_LDA], Al[32][FG_LDA];   // 5 KB
    __shared__ unsigned short Bh[64][FG_LDA], Bl[64][FG_LDA];   // 10 KB
    __shared__ int flag;
    int t = threadIdx.x;               // 256
    int bn = blockIdx.x;               // 16 col tiles of 64
    int bm = blockIdx.y;               // 16 row tiles of 32
    if (t == 0) flag = sniff_f32((const unsigned short*)s);
    __syncthreads();
    int f32 = flag;

    int w  = t >> 6, l = t & 63;
    int wm = w >> 1, wn = w & 1;
    int lr = l & 15, lq = l >> 4;

    int am = t >> 3, aq = t & 7;
    int bc = t >> 2, bq = t & 3;

    f32x4 acc0 = {0.f, 0.f, 0.f, 0.f};
    f32x4 acc1 = {0.f, 0.f, 0.f, 0.f};

    const float* arow = &cat[(bm * 32 + am) * 2112];

    for (int kt = 0; kt < 2112 / 32; ++kt) {
        {
            float4 xv = *(const float4*)&arow[kt * 32 + aq * 4];
            unsigned int p0 = split_bf16(xv.x);
            unsigned int p1 = split_bf16(xv.y);
            unsigned int p2 = split_bf16(xv.z);
            unsigned int p3 = split_bf16(xv.w);
            u16x4 hh, ll;
            hh[0] = (unsigned short)p0; ll[0] = (unsigned short)(p0 >> 16);
            hh[1] = (unsigned short)p1; ll[1] = (unsigned short)(p1 >> 16);
            hh[2] = (unsigned short)p2; ll[2] = (unsigned short)(p2 >> 16);
            hh[3] = (unsigned short)p3; ll[3] = (unsigned short)(p3 >> 16);
            *(u16x4*)&Ah[am][aq * 4] = hh;
            *(u16x4*)&Al[am][aq * 4] = ll;
        }
        {
            int kbase = kt * 32 + bq * 8;
            u16x8 hh, ll;
            #pragma unroll
            for (int e = 0; e < 8; ++e) {
                float x = ld(Wout, (kbase + e) * CS + bn * 64 + bc, f32);
                unsigned int pe = split_bf16(x);
                hh[e] = (unsigned short)pe;
                ll[e] = (unsigned short)(pe >> 16);
            }
            *(u16x8*)&Bh[bc][bq * 8] = hh;
            *(u16x8*)&Bl[bc][bq * 8] = ll;
        }
        __syncthreads();
        bf16x8 a_h = *(const bf16x8*)&Ah[wm * 16 + lr][lq * 8];
        bf16x8 a_l = *(const bf16x8*)&Al[wm * 16 + lr][lq * 8];
        bf16x8 b0h = *(const bf16x8*)&Bh[wn * 32 + lr][lq * 8];
        bf16x8 b0l = *(const bf16x8*)&Bl[wn * 32 + lr][lq * 8];
        bf16x8 b1h = *(const bf16x8*)&Bh[wn * 32 + 16 + lr][lq * 8];
        bf16x8 b1l = *(const bf16x8*)&Bl[wn * 32 + 16 + lr][lq * 8];
        acc0 = __builtin_amdgcn_mfma_f32_16x16x32_bf16(a_h, b0h, acc0, 0, 0, 0);
        acc0 = __builtin_amdgcn_mfma_f32_16x16x32_bf16(a_h, b0l, acc0, 0, 0, 0);
        acc0 = __builtin_amdgcn_mfma_f32_16x16x32_bf16(a_l, b0h, acc0, 0, 0, 0);
        acc1 = __builtin_amdgcn_mfma_f32_16x16x32_bf16(a_h, b1h, acc1, 0, 0, 0);
        acc1 = __builtin_amdgcn_mfma_f32_16x16x32_bf16(a_h, b1l, acc1, 0, 0, 0);
        acc1 = __builtin_amdgcn_mfma_f32_16x16x32_bf16(a_l, b1h, acc1, 0, 0, 0);
        __syncthreads();
    }

    int col0 = bn * 64 + wn * 32 + lr;
    int row0 = bm * 32 + wm * 16 + lq * 4;
    float bv0 = ld(bout, col0, f32);
    float bv1 = ld(bout, col0 + 16, f32);
    if (f32) {
        float* o = (float*)out;
        #pragma unroll
        for (int r = 0; r < 4; ++r) {
            o[(row0 + r) * CS + col0]      = acc0[r] + bv0;
            o[(row0 + r) * CS + col0 + 16] = acc1[r] + bv1;
        }
    } else {
        __hip_bfloat16* o = (__hip_bfloat16*)out;
        #pragma unroll
        for (int r = 0; r < 4; ++r) {
            o[(row0 + r) * CS + col0]      = __float2bfloat16(acc0[r] + bv0);
            o[(row0 + r) * CS + col0 + 16] = __float2bfloat16(acc1[r] + bv1);
        }
    }
}

extern "C" void kernel_launch(void* const* d_in, const int* in_sizes, int n_in,
                              void* d_out, int out_size, void* d_ws, size_t ws_size,
                              hipStream_t stream)
{
    const void* s      = d_in[0];
    const void* z      = d_in[1];
    const void* rot    = d_in[2];
    const void* trans  = d_in[3];
    const void* mask   = d_in[4];
    const void* Wq     = d_in[5];  const void* bq   = d_in[6];
    const void* Wkv    = d_in[7];  const void* bkv  = d_in[8];
    const void* Wqp    = d_in[9];  const void* bqp  = d_in[10];
    const void* Wkvp   = d_in[11]; const void* bkvp = d_in[12];
    const void* Wb     = d_in[13]; const void* bb   = d_in[14];
    const void* head_w = d_in[15];
    const void* Wout   = d_in[16]; const void* bout = d_in[17];

    float* w   = (float*)d_ws;          // total 1,671,168 floats = 6.4 MB
    float* q   = w;                     // 512*192
    float* k   = q  + 98304;
    float* v   = k  + 98304;
    float* qp  = v  + 98304;            // 512*144
    float* kp  = qp + 73728;
    float* vp  = kp + 73728;            // 512*288
    float* cat = vp + 147456;           // 512*2112
    float* rawP = cat;                  // 512*1152, aliases cat (dead before attn)
    (void)ws_size; (void)in_sizes; (void)n_in; (void)out_size;

    proj_gemm <<<dim3(18, 16), 256, 0, stream>>>(s, Wq, Wkv, Wqp, Wkvp, rawP);
    proj_post <<<512, 576, 0, stream>>>(rawP, bq, bkv, bqp, bkvp, rot, trans, s,
                                        q, k, v, qp, kp, vp);
    attn_fused<<<512, 512, 0, stream>>>(q, k, v, qp, kp, vp, z, Wb, bb, head_w, mask,
                                        rot, trans, s, cat);
    final_gemm<<<dim3(16, 16), 256, 0, stream>>>(cat, Wout, bout, d_out, s);
}

// Round 7
// 457.172 us; speedup vs baseline: 2.3556x; 1.1169x over previous
//
#include <hip/hip_runtime.h>
#include <hip/hip_bf16.h>

#define N 512
#define CS 1024
#define CZ 128
#define H 12
#define HD 16

// ---------------------------------------------------------------------------
// dtype sniff: 1 if buffer holds f32, 0 if bf16. Reads 32 16-bit words.
// ---------------------------------------------------------------------------
__device__ int sniff_f32(const unsigned short* p) {
    int bad = 0;
    for (int i = 0; i < 32; ++i) {
        unsigned short u = p[i];
        int e = (u >> 7) & 0xFF;
        if (e == 0xFF || e >= 141 || (e <= 27 && (u & 0x7FFFu) != 0)) bad++;
    }
    return bad > 0;
}

__device__ __forceinline__ float ld(const void* p, int i, int f32) {
    return f32 ? ((const float*)p)[i]
               : __bfloat162float(((const __hip_bfloat16*)p)[i]);
}

__device__ __forceinline__ float bfu(unsigned short u) {
    return __bfloat162float(*(const __hip_bfloat16*)&u);
}

// ---------------------------------------------------------------------------
// split-precision helpers for f32-accurate bf16 MFMA:
// x = hi + lo (hi = bf16(x), lo = bf16(x-hi)); A*B = Ah*Bh + Ah*Bl + Al*Bh.
// ---------------------------------------------------------------------------
typedef __attribute__((ext_vector_type(8))) short bf16x8;
typedef __attribute__((ext_vector_type(4))) float f32x4;
typedef __attribute__((ext_vector_type(4))) unsigned short u16x4;
typedef __attribute__((ext_vector_type(8))) unsigned short u16x8;

#define FG_LDA 40   // padded row length (bf16 elems) for 32-k tiles

// returns hi bf16 in low 16 bits, lo bf16 in high 16 bits
__device__ __forceinline__ unsigned int split_bf16(float x) {
    __hip_bfloat16 hb = __float2bfloat16(x);
    float hf = __bfloat162float(hb);
    __hip_bfloat16 lb = __float2bfloat16(x - hf);
    unsigned int h = *reinterpret_cast<unsigned short*>(&hb);
    unsigned int l = *reinterpret_cast<unsigned short*>(&lb);
    return h | (l << 16);
}

// ---------------------------------------------------------------------------
// K1: proj_gemm — rawP = s @ [Wq | Wkv | Wqp | Wkvp]  (512 x 1152, K=1024)
// split-bf16 MFMA, tile 32x64x32, 256 thr = 4 waves (2x2), grid (18,16).
// ---------------------------------------------------------------------------
__device__ __forceinline__ void wcat_resolve(int col,
        const void* Wq, const void* Wkv, const void* Wqp, const void* Wkvp,
        const void*& W, int& cc, int& ldim) {
    if (col < 192)      { W = Wq;   cc = col;       ldim = 192; }
    else if (col < 576) { W = Wkv;  cc = col - 192; ldim = 384; }
    else if (col < 720) { W = Wqp;  cc = col - 576; ldim = 144; }
    else                { W = Wkvp; cc = col - 720; ldim = 432; }
}

__global__ void proj_gemm(const void* s,
                          const void* Wq, const void* Wkv,
                          const void* Wqp, const void* Wkvp,
                          float* rawP)
{
    __shared__ unsigned short Ah[32][FG_LDA], Al[32][FG_LDA];
    __shared__ unsigned short Bh[64][FG_LDA], Bl[64][FG_LDA];
    __shared__ int flag;
    int t = threadIdx.x;               // 256
    int bn = blockIdx.x;               // 18 col tiles of 64
    int bm = blockIdx.y;               // 16 row tiles of 32
    if (t == 0) flag = sniff_f32((const unsigned short*)s);
    __syncthreads();
    int f32 = flag;

    int w  = t >> 6, l = t & 63;
    int wm = w >> 1, wn = w & 1;
    int lr = l & 15, lq = l >> 4;

    int am = t >> 3, aq = t & 7;       // A: row am, 4 vals at aq*4
    int bc = t >> 2, bq = t & 3;       // B: col bc, 8 k's at bq*8

    const void* Wsrc; int wcc, wld;
    wcat_resolve(bn * 64 + bc, Wq, Wkv, Wqp, Wkvp, Wsrc, wcc, wld);

    f32x4 acc0 = {0.f, 0.f, 0.f, 0.f};
    f32x4 acc1 = {0.f, 0.f, 0.f, 0.f};

    int arowbase = (bm * 32 + am) * CS;

    for (int kt = 0; kt < CS / 32; ++kt) {
        {
            int base = arowbase + kt * 32 + aq * 4;
            u16x4 hh, ll;
            #pragma unroll
            for (int e = 0; e < 4; ++e) {
                unsigned int pe = split_bf16(ld(s, base + e, f32));
                hh[e] = (unsigned short)pe; ll[e] = (unsigned short)(pe >> 16);
            }
            *(u16x4*)&Ah[am][aq * 4] = hh;
            *(u16x4*)&Al[am][aq * 4] = ll;
        }
        {
            int kbase = kt * 32 + bq * 8;
            u16x8 hh, ll;
            #pragma unroll
            for (int e = 0; e < 8; ++e) {
                unsigned int pe = split_bf16(ld(Wsrc, (kbase + e) * wld + wcc, f32));
                hh[e] = (unsigned short)pe; ll[e] = (unsigned short)(pe >> 16);
            }
            *(u16x8*)&Bh[bc][bq * 8] = hh;
            *(u16x8*)&Bl[bc][bq * 8] = ll;
        }
        __syncthreads();
        bf16x8 a_h = *(const bf16x8*)&Ah[wm * 16 + lr][lq * 8];
        bf16x8 a_l = *(const bf16x8*)&Al[wm * 16 + lr][lq * 8];
        bf16x8 b0h = *(const bf16x8*)&Bh[wn * 32 + lr][lq * 8];
        bf16x8 b0l = *(const bf16x8*)&Bl[wn * 32 + lr][lq * 8];
        bf16x8 b1h = *(const bf16x8*)&Bh[wn * 32 + 16 + lr][lq * 8];
        bf16x8 b1l = *(const bf16x8*)&Bl[wn * 32 + 16 + lr][lq * 8];
        acc0 = __builtin_amdgcn_mfma_f32_16x16x32_bf16(a_h, b0h, acc0, 0, 0, 0);
        acc0 = __builtin_amdgcn_mfma_f32_16x16x32_bf16(a_h, b0l, acc0, 0, 0, 0);
        acc0 = __builtin_amdgcn_mfma_f32_16x16x32_bf16(a_l, b0h, acc0, 0, 0, 0);
        acc1 = __builtin_amdgcn_mfma_f32_16x16x32_bf16(a_h, b1h, acc1, 0, 0, 0);
        acc1 = __builtin_amdgcn_mfma_f32_16x16x32_bf16(a_h, b1l, acc1, 0, 0, 0);
        acc1 = __builtin_amdgcn_mfma_f32_16x16x32_bf16(a_l, b1h, acc1, 0, 0, 0);
        __syncthreads();
    }

    int col0 = bn * 64 + wn * 32 + lr;
    int row0 = bm * 32 + wm * 16 + lq * 4;
    #pragma unroll
    for (int r = 0; r < 4; ++r) {
        rawP[(row0 + r) * 1152 + col0]      = acc0[r];
        rawP[(row0 + r) * 1152 + col0 + 16] = acc1[r];
    }
}

// ---------------------------------------------------------------------------
// K2: proj_post — bias add + q/k/v scatter + point rotation.
// k and kp stored TRANSPOSED (kT[192][512], kpT[144][512]) so that
// attn Phase B (thread = key j) reads them with lane-consecutive addresses.
// ---------------------------------------------------------------------------
__global__ void proj_post(const float* rawP,
                          const void* bq, const void* bkv,
                          const void* bqp, const void* bkvp,
                          const void* rot, const void* trans, const void* s,
                          float* q, float* kT, float* v,
                          float* qp, float* kpT, float* vp)
{
    __shared__ float rawL[576];
    __shared__ float R[9], T[3];
    __shared__ int flag;
    int t = threadIdx.x;     // 576
    int i = blockIdx.x;
    if (t == 0) flag = sniff_f32((const unsigned short*)s);
    __syncthreads();
    int f32 = flag;

    // qkv scatter
    {
        float val = rawP[i * 1152 + t];
        if (t < 192) q[i * 192 + t] = val + ld(bq, t, f32);
        else {
            int cc = t - 192;
            float vv = val + ld(bkv, cc, f32);
            int h = cc >> 5, t2 = cc & 31;
            if (t2 < 16) kT[(h * 16 + t2) * 512 + i] = vv;
            else         v[i * 192 + h * 16 + (t2 - 16)] = vv;
        }
    }
    // points: bias + stage
    rawL[t] = rawP[i * 1152 + 576 + t]
            + (t < 144 ? ld(bqp, t, f32) : ld(bkvp, t - 144, f32));
    if (t < 9) R[t] = ld(rot, i * 9 + t, f32);
    if (t >= 16 && t < 19) T[t - 16] = ld(trans, i * 3 + (t - 16), f32);
    __syncthreads();
    if (t < 192) {
        float x, y, zc;
        if (t < 48) { x = rawL[t];        y = rawL[48 + t];   zc = rawL[96 + t]; }
        else { int pk = t - 48;
               x = rawL[144 + pk]; y = rawL[288 + pk]; zc = rawL[432 + pk]; }
        float rx = R[0]*x + R[1]*y + R[2]*zc + T[0];
        float ry = R[3]*x + R[4]*y + R[5]*zc + T[1];
        float rz = R[6]*x + R[7]*y + R[8]*zc + T[2];
        if (t < 48) {
            int h = t >> 2, pp = t & 3, b = i * 144 + h * 12 + pp * 3;
            qp[b] = rx; qp[b + 1] = ry; qp[b + 2] = rz;
        } else {
            int pk = t - 48, h = pk / 12, idx = pk % 12;
            if (idx < 4) {
                int row = h * 12 + idx * 3;
                kpT[(row + 0) * 512 + i] = rx;
                kpT[(row + 1) * 512 + i] = ry;
                kpT[(row + 2) * 512 + i] = rz;
            } else {
                int b = i * 288 + h * 24 + (idx - 4) * 3;
                vp[b] = rx; vp[b + 1] = ry; vp[b + 2] = rz;
            }
        }
    }
}

// ---------------------------------------------------------------------------
// K3: fused bias + logits + softmax + (o, o_pt, o_pair) per query row i.
// Bias b = z[i]@Wb computed via cooperative 32-row z tiles staged in LDS
// (coalesced loads, fp32 - same accumulation order as reference).
// qk/pt read kT/kpT transposed -> lane-consecutive (4 lines/instr, L2-hit).
// LDS: attL 24K + WbL 6K + U(zT tile 16.5K | pairP 24K) + small = 56.8 KB.
// ---------------------------------------------------------------------------
__global__ void attn_fused(const float* q, const float* kT, const float* v,
                           const float* qp, const float* kpT, const float* vp,
                           const void* z, const void* Wb, const void* bb,
                           const void* head_w, const void* mask,
                           const void* rot, const void* trans, const void* s,
                           float* cat)
{
    __shared__ float attL[H * N];        // 24 KB
    __shared__ float WbL[CZ * H];        // 6 KB
    __shared__ float U[6144];            // 24 KB: zT tile (32x132) / pairP
    __shared__ float qL[192], qpL[144];
    __shared__ float RL[9], TL[3], bbL[H], hwL[H];
    __shared__ float miS;
    __shared__ int flag;
    int t = threadIdx.x;   // 512
    int i = blockIdx.x;
    if (t == 0) flag = sniff_f32((const unsigned short*)s);
    __syncthreads();
    int f32 = flag;
    for (int idx = t; idx < CZ * H; idx += 512) WbL[idx] = ld(Wb, idx, f32);
    if (t < 192) qL[t] = q[i * 192 + t];
    else if (t < 336) qpL[t - 192] = qp[i * 144 + (t - 192)];
    else if (t < 345) RL[t - 336] = ld(rot, i * 9 + (t - 336), f32);
    else if (t < 348) TL[t - 345] = ld(trans, i * 3 + (t - 345), f32);
    else if (t < 360) bbL[t - 348] = ld(bb, t - 348, f32);
    else if (t < 372) {
        float x = ld(head_w, t - 360, f32);
        float sp = (x > 20.f) ? x : log1pf(expf(x));
        hwL[t - 360] = sp * 0.13608276348795434f;   // softplus * sqrt(1/54)
    }
    else if (t == 372) miS = ld(mask, i, f32);
    __syncthreads();

    // ---- Phase A: bias b = bb + z[i]@Wb via cooperative 32-j z tiles ----
    // zT tile: 32 rows x 132 (pad; stride%32=4 -> conflict-free col walk)
    {
        int jl = t >> 4, hs = t & 15;    // compute mapping: 32 j x 16 h-slots
        for (int jt = 0; jt < 16; ++jt) {
            __syncthreads();             // previous tile fully consumed
            if (f32) {
                const float* zrow = (const float*)z + (i * N + jt * 32) * CZ;
                #pragma unroll
                for (int r = 0; r < 2; ++r) {
                    int flat = (t + 512 * r) * 4;
                    int row = flat >> 7, col = flat & 127;
                    float4 vz = *(const float4*)&zrow[flat];
                    *(float4*)&U[row * 132 + col] = vz;
                }
            } else {
                const unsigned short* zrow =
                    (const unsigned short*)z + (i * N + jt * 32) * CZ;
                int flat = t * 8;
                int row = flat >> 7, col = flat & 127;
                u16x8 uv = *(const u16x8*)&zrow[flat];
                float4 lo = {bfu(uv[0]), bfu(uv[1]), bfu(uv[2]), bfu(uv[3])};
                float4 hi = {bfu(uv[4]), bfu(uv[5]), bfu(uv[6]), bfu(uv[7])};
                *(float4*)&U[row * 132 + col] = lo;
                *(float4*)&U[row * 132 + col + 4] = hi;
            }
            __syncthreads();
            if (hs < H) {
                float acc = bbL[hs];
                #pragma unroll 8
                for (int c = 0; c < CZ; ++c)
                    acc += U[jl * 132 + c] * WbL[c * H + hs];
                attL[hs * N + jt * 32 + jl] = acc;
            }
        }
    }
    __syncthreads();

    // ---- Phase B: logits, thread = key index j; kT/kpT lane-coalesced ----
    {
        int j = t;
        float mj = ld(mask, j, f32);
        float mterm = 100000.0f * (miS * mj - 1.0f);
        const float* kTj  = kT + j;
        const float* kpTj = kpT + j;
        float bj[H];
        #pragma unroll
        for (int h = 0; h < H; ++h) bj[h] = attL[h * N + j];
        for (int h = 0; h < H; ++h) {
            float qk = 0.f;
            #pragma unroll
            for (int d = 0; d < 16; ++d)
                qk += qL[h * 16 + d] * kTj[(h * 16 + d) * 512];
            float pt = 0.f;
            #pragma unroll
            for (int p = 0; p < 4; ++p) {
                float dx = qpL[h*12 + p*3 + 0] - kpTj[(h*12 + p*3 + 0) * 512];
                float dy = qpL[h*12 + p*3 + 1] - kpTj[(h*12 + p*3 + 1) * 512];
                float dz = qpL[h*12 + p*3 + 2] - kpTj[(h*12 + p*3 + 2) * 512];
                pt += dx * dx + dy * dy + dz * dz;
            }
            attL[h * N + j] = qk * 0.14433756729740643f     // sqrt(1/48)
                            + 0.5773502691896258f * bj[h]   // sqrt(1/3)
                            - 0.5f * hwL[h] * pt + mterm;
        }
    }
    __syncthreads();

    // ---- Phase C: softmax per head (one wave per head) ----
    {
        int w = t >> 6, l = t & 63;
        for (int h = w; h < H; h += 8) {
            float av[8];
            #pragma unroll
            for (int kk = 0; kk < 8; ++kk) av[kk] = attL[h * N + kk * 64 + l];
            float m = av[0];
            #pragma unroll
            for (int kk = 1; kk < 8; ++kk) m = fmaxf(m, av[kk]);
            for (int off = 1; off < 64; off <<= 1) m = fmaxf(m, __shfl_xor(m, off));
            float ssum = 0.f;
            #pragma unroll
            for (int kk = 0; kk < 8; ++kk) { av[kk] = __expf(av[kk] - m); ssum += av[kk]; }
            for (int off = 1; off < 64; off <<= 1) ssum += __shfl_xor(ssum, off);
            float inv = 1.0f / ssum;
            #pragma unroll
            for (int kk = 0; kk < 8; ++kk) attL[h * N + kk * 64 + l] = av[kk] * inv;
        }
    }
    __syncthreads();

    // ---- Phase D1: o = a@v (192 thr), o_pt + inv-frame + norm (96 thr) ----
    if (t < 192) {
        int h = t >> 4, d = t & 15;
        float acc = 0.f;
        for (int j = 0; j < N; ++j) acc += attL[h * N + j] * v[j * 192 + h * 16 + d];
        cat[i * 2112 + t] = acc;
    } else if (t < 288) {
        int hp = t - 192, h = hp >> 3, p = hp & 7;
        float ax = 0, ay = 0, az = 0;
        for (int j = 0; j < N; ++j) {
            float a_ = attL[h * N + j];
            int b2 = j * 288 + h * 24 + p * 3;
            ax += a_ * vp[b2]; ay += a_ * vp[b2 + 1]; az += a_ * vp[b2 + 2];
        }
        float gx = ax - TL[0], gy = ay - TL[1], gz = az - TL[2];
        float lx = RL[0]*gx + RL[3]*gy + RL[6]*gz;   // R^T
        float ly = RL[1]*gx + RL[4]*gy + RL[7]*gz;
        float lz = RL[2]*gx + RL[5]*gy + RL[8]*gz;
        float nrm = sqrtf(lx*lx + ly*ly + lz*lz + 1e-8f);
        cat[i * 2112 + 192 + hp] = lx;
        cat[i * 2112 + 288 + hp] = ly;
        cat[i * 2112 + 384 + hp] = lz;
        cat[i * 2112 + 480 + hp] = nrm;
    }

    // ---- Phase D2: o_pair = a @ z[i]  (all 512 threads, 4 j-quarters) ----
    {
        int quarter = t >> 7, c = t & 127;
        float pacc[H];
        #pragma unroll
        for (int h = 0; h < H; ++h) pacc[h] = 0.f;
        int j0 = quarter * 128;
        if (f32) {
            const float* zp = (const float*)z + (i * N + j0) * CZ + c;
            for (int j = 0; j < 128; ++j) {
                float zc = zp[j * CZ];
                #pragma unroll
                for (int h = 0; h < H; ++h) pacc[h] += attL[h * N + j0 + j] * zc;
            }
        } else {
            const unsigned short* zp =
                (const unsigned short*)z + (i * N + j0) * CZ + c;
            for (int j = 0; j < 128; ++j) {
                float zc = bfu(zp[j * CZ]);
                #pragma unroll
                for (int h = 0; h < H; ++h) pacc[h] += attL[h * N + j0 + j] * zc;
            }
        }
        __syncthreads();   // U free (zT dead since Phase A)
        #pragma unroll
        for (int h = 0; h < H; ++h) U[quarter * (H * CZ) + h * CZ + c] = pacc[h];
    }
    __syncthreads();
    for (int idx = t; idx < H * CZ; idx += 512)
        cat[i * 2112 + 576 + idx] =
            U[idx] + U[1536 + idx] + U[3072 + idx] + U[4608 + idx];
}

// ---------------------------------------------------------------------------
// K4: out = cat @ Wout + bout via split-precision bf16 MFMA (unchanged).
// ---------------------------------------------------------------------------
__global__ void final_gemm(const float* cat, const void* Wout, const void* bout,
                           void* out, const void* s)
{
    __shared__ unsigned short Ah[32][FG_LDA], Al[32][FG_LDA];   // 5 KB
    __shared__ unsigned short Bh[64][FG_LDA], Bl[64][FG_LDA];   // 10 KB
    __shared__ int flag;
    int t = threadIdx.x;               // 256
    int bn = blockIdx.x;               // 16 col tiles of 64
    int bm = blockIdx.y;               // 16 row tiles of 32
    if (t == 0) flag = sniff_f32((const unsigned short*)s);
    __syncthreads();
    int f32 = flag;

    int w  = t >> 6, l = t & 63;
    int wm = w >> 1, wn = w & 1;
    int lr = l & 15, lq = l >> 4;

    int am = t >> 3, aq = t & 7;
    int bc = t >> 2, bq = t & 3;

    f32x4 acc0 = {0.f, 0.f, 0.f, 0.f};
    f32x4 acc1 = {0.f, 0.f, 0.f, 0.f};

    const float* arow = &cat[(bm * 32 + am) * 2112];

    for (int kt = 0; kt < 2112 / 32; ++kt) {
        {
            float4 xv = *(const float4*)&arow[kt * 32 + aq * 4];
            unsigned int p0 = split_bf16(xv.x);
            unsigned int p1 = split_bf16(xv.y);
            unsigned int p2 = split_bf16(xv.z);
            unsigned int p3 = split_bf16(xv.w);
            u16x4 hh, ll;
            hh[0] = (unsigned short)p0; ll[0] = (unsigned short)(p0 >> 16);
            hh[1] = (unsigned short)p1; ll[1] = (unsigned short)(p1 >> 16);
            hh[2] = (unsigned short)p2; ll[2] = (unsigned short)(p2 >> 16);
            hh[3] = (unsigned short)p3; ll[3] = (unsigned short)(p3 >> 16);
            *(u16x4*)&Ah[am][aq * 4] = hh;
            *(u16x4*)&Al[am][aq * 4] = ll;
        }
        {
            int kbase = kt * 32 + bq * 8;
            u16x8 hh, ll;
            #pragma unroll
            for (int e = 0; e < 8; ++e) {
                float x = ld(Wout, (kbase + e) * CS + bn * 64 + bc, f32);
                unsigned int pe = split_bf16(x);
                hh[e] = (unsigned short)pe;
                ll[e] = (unsigned short)(pe >> 16);
            }
            *(u16x8*)&Bh[bc][bq * 8] = hh;
            *(u16x8*)&Bl[bc][bq * 8] = ll;
        }
        __syncthreads();
        bf16x8 a_h = *(const bf16x8*)&Ah[wm * 16 + lr][lq * 8];
        bf16x8 a_l = *(const bf16x8*)&Al[wm * 16 + lr][lq * 8];
        bf16x8 b0h = *(const bf16x8*)&Bh[wn * 32 + lr][lq * 8];
        bf16x8 b0l = *(const bf16x8*)&Bl[wn * 32 + lr][lq * 8];
        bf16x8 b1h = *(const bf16x8*)&Bh[wn * 32 + 16 + lr][lq * 8];
        bf16x8 b1l = *(const bf16x8*)&Bl[wn * 32 + 16 + lr][lq * 8];
        acc0 = __builtin_amdgcn_mfma_f32_16x16x32_bf16(a_h, b0h, acc0, 0, 0, 0);
        acc0 = __builtin_amdgcn_mfma_f32_16x16x32_bf16(a_h, b0l, acc0, 0, 0, 0);
        acc0 = __builtin_amdgcn_mfma_f32_16x16x32_bf16(a_l, b0h, acc0, 0, 0, 0);
        acc1 = __builtin_amdgcn_mfma_f32_16x16x32_bf16(a_h, b1h, acc1, 0, 0, 0);
        acc1 = __builtin_amdgcn_mfma_f32_16x16x32_bf16(a_h, b1l, acc1, 0, 0, 0);
        acc1 = __builtin_amdgcn_mfma_f32_16x16x32_bf16(a_l, b1h, acc1, 0, 0, 0);
        __syncthreads();
    }

    int col0 = bn * 64 + wn * 32 + lr;
    int row0 = bm * 32 + wm * 16 + lq * 4;
    float bv0 = ld(bout, col0, f32);
    float bv1 = ld(bout, col0 + 16, f32);
    if (f32) {
        float* o = (float*)out;
        #pragma unroll
        for (int r = 0; r < 4; ++r) {
            o[(row0 + r) * CS + col0]      = acc0[r] + bv0;
            o[(row0 + r) * CS + col0 + 16] = acc1[r] + bv1;
        }
    } else {
        __hip_bfloat16* o = (__hip_bfloat16*)out;
        #pragma unroll
        for (int r = 0; r < 4; ++r) {
            o[(row0 + r) * CS + col0]      = __float2bfloat16(acc0[r] + bv0);
            o[(row0 + r) * CS + col0 + 16] = __float2bfloat16(acc1[r] + bv1);
        }
    }
}

extern "C" void kernel_launch(void* const* d_in, const int* in_sizes, int n_in,
                              void* d_out, int out_size, void* d_ws, size_t ws_size,
                              hipStream_t stream)
{
    const void* s      = d_in[0];
    const void* z      = d_in[1];
    const void* rot    = d_in[2];
    const void* trans  = d_in[3];
    const void* mask   = d_in[4];
    const void* Wq     = d_in[5];  const void* bq   = d_in[6];
    const void* Wkv    = d_in[7];  const void* bkv  = d_in[8];
    const void* Wqp    = d_in[9];  const void* bqp  = d_in[10];
    const void* Wkvp   = d_in[11]; const void* bkvp = d_in[12];
    const void* Wb     = d_in[13]; const void* bb   = d_in[14];
    const void* head_w = d_in[15];
    const void* Wout   = d_in[16]; const void* bout = d_in[17];

    float* w    = (float*)d_ws;         // total 1,671,168 floats = 6.4 MB
    float* q    = w;                    // 512*192
    float* kT   = q   + 98304;          // [192][512] transposed
    float* v    = kT  + 98304;          // 512*192
    float* qp   = v   + 98304;          // 512*144
    float* kpT  = qp  + 73728;          // [144][512] transposed
    float* vp   = kpT + 73728;          // 512*288
    float* cat  = vp  + 147456;         // 512*2112
    float* rawP = cat;                  // 512*1152, aliases cat (dead before attn)
    (void)ws_size; (void)in_sizes; (void)n_in; (void)out_size;

    proj_gemm <<<dim3(18, 16), 256, 0, stream>>>(s, Wq, Wkv, Wqp, Wkvp, rawP);
    proj_post <<<512, 576, 0, stream>>>(rawP, bq, bkv, bqp, bkvp, rot, trans, s,
                                        q, kT, v, qp, kpT, vp);
    attn_fused<<<512, 512, 0, stream>>>(q, kT, v, qp, kpT, vp, z, Wb, bb, head_w, mask,
                                        rot, trans, s, cat);
    final_gemm<<<dim3(16, 16), 256, 0, stream>>>(cat, Wout, bout, d_out, s);
}

// Round 8
// 435.161 us; speedup vs baseline: 2.4747x; 1.0506x over previous
//
#include <hip/hip_runtime.h>
#include <hip/hip_bf16.h>

#define N 512
#define CS 1024
#define CZ 128
#define H 12
#define HD 16
#define KC 2112   // final gemm K (cat width)

// ---------------------------------------------------------------------------
// dtype sniff: 1 if buffer holds f32, 0 if bf16. Reads 32 16-bit words.
// ---------------------------------------------------------------------------
__device__ int sniff_f32(const unsigned short* p) {
    int bad = 0;
    for (int i = 0; i < 32; ++i) {
        unsigned short u = p[i];
        int e = (u >> 7) & 0xFF;
        if (e == 0xFF || e >= 141 || (e <= 27 && (u & 0x7FFFu) != 0)) bad++;
    }
    return bad > 0;
}

__device__ __forceinline__ float ld(const void* p, int i, int f32) {
    return f32 ? ((const float*)p)[i]
               : __bfloat162float(((const __hip_bfloat16*)p)[i]);
}

__device__ __forceinline__ float bfu(unsigned short u) {
    return __bfloat162float(*(const __hip_bfloat16*)&u);
}

// ---------------------------------------------------------------------------
// split-precision helpers for f32-accurate bf16 MFMA:
// x = hi + lo (hi = bf16(x), lo = bf16(x-hi)); A*B = Ah*Bh + Ah*Bl + Al*Bh.
// ---------------------------------------------------------------------------
typedef __attribute__((ext_vector_type(8))) short bf16x8;
typedef __attribute__((ext_vector_type(4))) float f32x4;
typedef __attribute__((ext_vector_type(8))) unsigned short u16x8;

// returns hi bf16 in low 16 bits, lo bf16 in high 16 bits
__device__ __forceinline__ unsigned int split_bf16(float x) {
    __hip_bfloat16 hb = __float2bfloat16(x);
    float hf = __bfloat162float(hb);
    __hip_bfloat16 lb = __float2bfloat16(x - hf);
    unsigned int h = *reinterpret_cast<unsigned short*>(&hb);
    unsigned int l = *reinterpret_cast<unsigned short*>(&lb);
    return h | (l << 16);
}

__device__ __forceinline__ void wcat_resolve(int col,
        const void* Wq, const void* Wkv, const void* Wqp, const void* Wkvp,
        const void*& W, int& cc, int& ldim) {
    if (col < 192)      { W = Wq;   cc = col;       ldim = 192; }
    else if (col < 576) { W = Wkv;  cc = col - 192; ldim = 384; }
    else if (col < 720) { W = Wqp;  cc = col - 576; ldim = 144; }
    else                { W = Wkvp; cc = col - 720; ldim = 432; }
}

// ---------------------------------------------------------------------------
// K0: prep_w — transpose + hi/lo-split ALL weight matrices once.
// WcatT_h/l [1152 cols][1024 k]  from Wq|Wkv|Wqp|Wkvp (each [k][cols])
// WoutT_h/l [1024 cols][2112 k]  from Wout [2112][1024]
// 32x32 tile transpose via LDS; coalesced reads AND writes.
// grid: 1152 (36x32) + 2112 (32x66) = 3264 blocks x 256 thr.
// ---------------------------------------------------------------------------
__global__ void prep_w(const void* Wq, const void* Wkv, const void* Wqp,
                       const void* Wkvp, const void* Wout, const void* s,
                       unsigned short* WcTh, unsigned short* WcTl,
                       unsigned short* WoTh, unsigned short* WoTl)
{
    __shared__ unsigned short th[32][33], tl[32][33];
    __shared__ int flag;
    int t = threadIdx.x;                 // 256
    if (t == 0) flag = sniff_f32((const unsigned short*)s);
    __syncthreads();
    int f32 = flag;
    int tx = t & 31, ty = t >> 5;        // ty 0..7
    int b = blockIdx.x;
    if (b < 1152) {
        int ct = b % 36, kt = b / 36;
        int c0 = ct * 32, k0 = kt * 32;
        #pragma unroll
        for (int r = 0; r < 4; ++r) {
            int k = k0 + ty + 8 * r, c = c0 + tx;
            const void* W; int cc, ldim;
            wcat_resolve(c, Wq, Wkv, Wqp, Wkvp, W, cc, ldim);
            unsigned int pe = split_bf16(ld(W, k * ldim + cc, f32));
            th[ty + 8 * r][tx] = (unsigned short)pe;
            tl[ty + 8 * r][tx] = (unsigned short)(pe >> 16);
        }
        __syncthreads();
        #pragma unroll
        for (int r = 0; r < 4; ++r) {
            int c = c0 + ty + 8 * r, k = k0 + tx;
            WcTh[c * CS + k] = th[tx][ty + 8 * r];
            WcTl[c * CS + k] = tl[tx][ty + 8 * r];
        }
    } else {
        int bb = b - 1152;
        int ct = bb & 31, kt = bb >> 5;   // 32 col tiles x 66 k tiles
        int c0 = ct * 32, k0 = kt * 32;
        #pragma unroll
        for (int r = 0; r < 4; ++r) {
            int k = k0 + ty + 8 * r, c = c0 + tx;
            unsigned int pe = split_bf16(ld(Wout, k * CS + c, f32));
            th[ty + 8 * r][tx] = (unsigned short)pe;
            tl[ty + 8 * r][tx] = (unsigned short)(pe >> 16);
        }
        __syncthreads();
        #pragma unroll
        for (int r = 0; r < 4; ++r) {
            int c = c0 + ty + 8 * r, k = k0 + tx;
            WoTh[c * KC + k] = th[tx][ty + 8 * r];
            WoTl[c * KC + k] = tl[tx][ty + 8 * r];
        }
    }
}

// ---------------------------------------------------------------------------
// K1: proj_gemm — rawP = s @ Wcat  (512 x 1152, K=1024), barrier-free.
// B-fragments load directly from pre-split transposed weights (per-lane
// u16x8 IS the MFMA fragment); A split in-register from f32/bf16 s.
// No LDS, no syncthreads in K-loop. Tile 32x64, 4 waves, grid (18,16).
// ---------------------------------------------------------------------------
__global__ void proj_gemm(const void* s, const unsigned short* BTh,
                          const unsigned short* BTl, float* rawP)
{
    __shared__ int flag;
    int t = threadIdx.x;               // 256
    int bn = blockIdx.x;               // 18 col tiles of 64
    int bm = blockIdx.y;               // 16 row tiles of 32
    if (t == 0) flag = sniff_f32((const unsigned short*)s);
    __syncthreads();
    int f32 = flag;

    int w  = t >> 6, l = t & 63;
    int wm = w >> 1, wn = w & 1;
    int lr = l & 15, lq = l >> 4;

    int arow = bm * 32 + wm * 16 + lr;
    int bcol = bn * 64 + wn * 32 + lr;
    const unsigned short* bh = BTh + bcol * CS;
    const unsigned short* bl = BTl + bcol * CS;

    f32x4 acc0 = {0.f, 0.f, 0.f, 0.f};
    f32x4 acc1 = {0.f, 0.f, 0.f, 0.f};

    #pragma unroll 2
    for (int kt = 0; kt < CS / 32; ++kt) {
        int kk = kt * 32 + lq * 8;
        u16x8 ah, al;
        if (f32) {
            const float* ap = (const float*)s + arow * CS + kk;
            #pragma unroll
            for (int e = 0; e < 8; ++e) {
                unsigned int pe = split_bf16(ap[e]);
                ah[e] = (unsigned short)pe; al[e] = (unsigned short)(pe >> 16);
            }
        } else {
            ah = *(const u16x8*)((const unsigned short*)s + arow * CS + kk);
            #pragma unroll
            for (int e = 0; e < 8; ++e) al[e] = 0;
        }
        bf16x8 b0h = *(const bf16x8*)(bh + kk);
        bf16x8 b0l = *(const bf16x8*)(bl + kk);
        bf16x8 b1h = *(const bf16x8*)(bh + 16 * CS + kk);
        bf16x8 b1l = *(const bf16x8*)(bl + 16 * CS + kk);
        bf16x8 a_h = *(bf16x8*)&ah;
        bf16x8 a_l = *(bf16x8*)&al;
        acc0 = __builtin_amdgcn_mfma_f32_16x16x32_bf16(a_h, b0h, acc0, 0, 0, 0);
        acc0 = __builtin_amdgcn_mfma_f32_16x16x32_bf16(a_h, b0l, acc0, 0, 0, 0);
        acc0 = __builtin_amdgcn_mfma_f32_16x16x32_bf16(a_l, b0h, acc0, 0, 0, 0);
        acc1 = __builtin_amdgcn_mfma_f32_16x16x32_bf16(a_h, b1h, acc1, 0, 0, 0);
        acc1 = __builtin_amdgcn_mfma_f32_16x16x32_bf16(a_h, b1l, acc1, 0, 0, 0);
        acc1 = __builtin_amdgcn_mfma_f32_16x16x32_bf16(a_l, b1h, acc1, 0, 0, 0);
    }

    int col0 = bn * 64 + wn * 32 + lr;
    int row0 = bm * 32 + wm * 16 + lq * 4;
    #pragma unroll
    for (int r = 0; r < 4; ++r) {
        rawP[(row0 + r) * 1152 + col0]      = acc0[r];
        rawP[(row0 + r) * 1152 + col0 + 16] = acc1[r];
    }
}

// ---------------------------------------------------------------------------
// K2: proj_post — bias add + q/k/v scatter + point rotation.
// k and kp stored TRANSPOSED (kT[192][512], kpT[144][512]).
// ---------------------------------------------------------------------------
__global__ void proj_post(const float* rawP,
                          const void* bq, const void* bkv,
                          const void* bqp, const void* bkvp,
                          const void* rot, const void* trans, const void* s,
                          float* q, float* kT, float* v,
                          float* qp, float* kpT, float* vp)
{
    __shared__ float rawL[576];
    __shared__ float R[9], T[3];
    __shared__ int flag;
    int t = threadIdx.x;     // 576
    int i = blockIdx.x;
    if (t == 0) flag = sniff_f32((const unsigned short*)s);
    __syncthreads();
    int f32 = flag;

    // qkv scatter
    {
        float val = rawP[i * 1152 + t];
        if (t < 192) q[i * 192 + t] = val + ld(bq, t, f32);
        else {
            int cc = t - 192;
            float vv = val + ld(bkv, cc, f32);
            int h = cc >> 5, t2 = cc & 31;
            if (t2 < 16) kT[(h * 16 + t2) * 512 + i] = vv;
            else         v[i * 192 + h * 16 + (t2 - 16)] = vv;
        }
    }
    // points: bias + stage
    rawL[t] = rawP[i * 1152 + 576 + t]
            + (t < 144 ? ld(bqp, t, f32) : ld(bkvp, t - 144, f32));
    if (t < 9) R[t] = ld(rot, i * 9 + t, f32);
    if (t >= 16 && t < 19) T[t - 16] = ld(trans, i * 3 + (t - 16), f32);
    __syncthreads();
    if (t < 192) {
        float x, y, zc;
        if (t < 48) { x = rawL[t];        y = rawL[48 + t];   zc = rawL[96 + t]; }
        else { int pk = t - 48;
               x = rawL[144 + pk]; y = rawL[288 + pk]; zc = rawL[432 + pk]; }
        float rx = R[0]*x + R[1]*y + R[2]*zc + T[0];
        float ry = R[3]*x + R[4]*y + R[5]*zc + T[1];
        float rz = R[6]*x + R[7]*y + R[8]*zc + T[2];
        if (t < 48) {
            int h = t >> 2, pp = t & 3, b = i * 144 + h * 12 + pp * 3;
            qp[b] = rx; qp[b + 1] = ry; qp[b + 2] = rz;
        } else {
            int pk = t - 48, h = pk / 12, idx = pk % 12;
            if (idx < 4) {
                int row = h * 12 + idx * 3;
                kpT[(row + 0) * 512 + i] = rx;
                kpT[(row + 1) * 512 + i] = ry;
                kpT[(row + 2) * 512 + i] = rz;
            } else {
                int b = i * 288 + h * 24 + (idx - 4) * 3;
                vp[b] = rx; vp[b + 1] = ry; vp[b + 2] = rz;
            }
        }
    }
}

// ---------------------------------------------------------------------------
// K3: fused bias + logits + softmax + (o, o_pt, o_pair) per query row i.
// (unchanged from round 7: coalesced z bias tiles + transposed kT/kpT)
// ---------------------------------------------------------------------------
__global__ void attn_fused(const float* q, const float* kT, const float* v,
                           const float* qp, const float* kpT, const float* vp,
                           const void* z, const void* Wb, const void* bb,
                           const void* head_w, const void* mask,
                           const void* rot, const void* trans, const void* s,
                           float* cat)
{
    __shared__ float attL[H * N];        // 24 KB
    __shared__ float WbL[CZ * H];        // 6 KB
    __shared__ float U[6144];            // 24 KB: zT tile (32x132) / pairP
    __shared__ float qL[192], qpL[144];
    __shared__ float RL[9], TL[3], bbL[H], hwL[H];
    __shared__ float miS;
    __shared__ int flag;
    int t = threadIdx.x;   // 512
    int i = blockIdx.x;
    if (t == 0) flag = sniff_f32((const unsigned short*)s);
    __syncthreads();
    int f32 = flag;
    for (int idx = t; idx < CZ * H; idx += 512) WbL[idx] = ld(Wb, idx, f32);
    if (t < 192) qL[t] = q[i * 192 + t];
    else if (t < 336) qpL[t - 192] = qp[i * 144 + (t - 192)];
    else if (t < 345) RL[t - 336] = ld(rot, i * 9 + (t - 336), f32);
    else if (t < 348) TL[t - 345] = ld(trans, i * 3 + (t - 345), f32);
    else if (t < 360) bbL[t - 348] = ld(bb, t - 348, f32);
    else if (t < 372) {
        float x = ld(head_w, t - 360, f32);
        float sp = (x > 20.f) ? x : log1pf(expf(x));
        hwL[t - 360] = sp * 0.13608276348795434f;   // softplus * sqrt(1/54)
    }
    else if (t == 372) miS = ld(mask, i, f32);
    __syncthreads();

    // ---- Phase A: bias b = bb + z[i]@Wb via cooperative 32-j z tiles ----
    {
        int jl = t >> 4, hs = t & 15;    // compute mapping: 32 j x 16 h-slots
        for (int jt = 0; jt < 16; ++jt) {
            __syncthreads();             // previous tile fully consumed
            if (f32) {
                const float* zrow = (const float*)z + (i * N + jt * 32) * CZ;
                #pragma unroll
                for (int r = 0; r < 2; ++r) {
                    int flat = (t + 512 * r) * 4;
                    int row = flat >> 7, col = flat & 127;
                    float4 vz = *(const float4*)&zrow[flat];
                    *(float4*)&U[row * 132 + col] = vz;
                }
            } else {
                const unsigned short* zrow =
                    (const unsigned short*)z + (i * N + jt * 32) * CZ;
                int flat = t * 8;
                int row = flat >> 7, col = flat & 127;
                u16x8 uv = *(const u16x8*)&zrow[flat];
                float4 lo = {bfu(uv[0]), bfu(uv[1]), bfu(uv[2]), bfu(uv[3])};
                float4 hi = {bfu(uv[4]), bfu(uv[5]), bfu(uv[6]), bfu(uv[7])};
                *(float4*)&U[row * 132 + col] = lo;
                *(float4*)&U[row * 132 + col + 4] = hi;
            }
            __syncthreads();
            if (hs < H) {
                float acc = bbL[hs];
                #pragma unroll 8
                for (int c = 0; c < CZ; ++c)
                    acc += U[jl * 132 + c] * WbL[c * H + hs];
                attL[hs * N + jt * 32 + jl] = acc;
            }
        }
    }
    __syncthreads();

    // ---- Phase B: logits, thread = key index j; kT/kpT lane-coalesced ----
    {
        int j = t;
        float mj = ld(mask, j, f32);
        float mterm = 100000.0f * (miS * mj - 1.0f);
        const float* kTj  = kT + j;
        const float* kpTj = kpT + j;
        float bj[H];
        #pragma unroll
        for (int h = 0; h < H; ++h) bj[h] = attL[h * N + j];
        for (int h = 0; h < H; ++h) {
            float qk = 0.f;
            #pragma unroll
            for (int d = 0; d < 16; ++d)
                qk += qL[h * 16 + d] * kTj[(h * 16 + d) * 512];
            float pt = 0.f;
            #pragma unroll
            for (int p = 0; p < 4; ++p) {
                float dx = qpL[h*12 + p*3 + 0] - kpTj[(h*12 + p*3 + 0) * 512];
                float dy = qpL[h*12 + p*3 + 1] - kpTj[(h*12 + p*3 + 1) * 512];
                float dz = qpL[h*12 + p*3 + 2] - kpTj[(h*12 + p*3 + 2) * 512];
                pt += dx * dx + dy * dy + dz * dz;
            }
            attL[h * N + j] = qk * 0.14433756729740643f     // sqrt(1/48)
                            + 0.5773502691896258f * bj[h]   // sqrt(1/3)
                            - 0.5f * hwL[h] * pt + mterm;
        }
    }
    __syncthreads();

    // ---- Phase C: softmax per head (one wave per head) ----
    {
        int w = t >> 6, l = t & 63;
        for (int h = w; h < H; h += 8) {
            float av[8];
            #pragma unroll
            for (int kk = 0; kk < 8; ++kk) av[kk] = attL[h * N + kk * 64 + l];
            float m = av[0];
            #pragma unroll
            for (int kk = 1; kk < 8; ++kk) m = fmaxf(m, av[kk]);
            for (int off = 1; off < 64; off <<= 1) m = fmaxf(m, __shfl_xor(m, off));
            float ssum = 0.f;
            #pragma unroll
            for (int kk = 0; kk < 8; ++kk) { av[kk] = __expf(av[kk] - m); ssum += av[kk]; }
            for (int off = 1; off < 64; off <<= 1) ssum += __shfl_xor(ssum, off);
            float inv = 1.0f / ssum;
            #pragma unroll
            for (int kk = 0; kk < 8; ++kk) attL[h * N + kk * 64 + l] = av[kk] * inv;
        }
    }
    __syncthreads();

    // ---- Phase D1: o = a@v (192 thr), o_pt + inv-frame + norm (96 thr) ----
    if (t < 192) {
        int h = t >> 4, d = t & 15;
        float acc = 0.f;
        for (int j = 0; j < N; ++j) acc += attL[h * N + j] * v[j * 192 + h * 16 + d];
        cat[i * 2112 + t] = acc;
    } else if (t < 288) {
        int hp = t - 192, h = hp >> 3, p = hp & 7;
        float ax = 0, ay = 0, az = 0;
        for (int j = 0; j < N; ++j) {
            float a_ = attL[h * N + j];
            int b2 = j * 288 + h * 24 + p * 3;
            ax += a_ * vp[b2]; ay += a_ * vp[b2 + 1]; az += a_ * vp[b2 + 2];
        }
        float gx = ax - TL[0], gy = ay - TL[1], gz = az - TL[2];
        float lx = RL[0]*gx + RL[3]*gy + RL[6]*gz;   // R^T
        float ly = RL[1]*gx + RL[4]*gy + RL[7]*gz;
        float lz = RL[2]*gx + RL[5]*gy + RL[8]*gz;
        float nrm = sqrtf(lx*lx + ly*ly + lz*lz + 1e-8f);
        cat[i * 2112 + 192 + hp] = lx;
        cat[i * 2112 + 288 + hp] = ly;
        cat[i * 2112 + 384 + hp] = lz;
        cat[i * 2112 + 480 + hp] = nrm;
    }

    // ---- Phase D2: o_pair = a @ z[i]  (all 512 threads, 4 j-quarters) ----
    {
        int quarter = t >> 7, c = t & 127;
        float pacc[H];
        #pragma unroll
        for (int h = 0; h < H; ++h) pacc[h] = 0.f;
        int j0 = quarter * 128;
        if (f32) {
            const float* zp = (const float*)z + (i * N + j0) * CZ + c;
            for (int j = 0; j < 128; ++j) {
                float zc = zp[j * CZ];
                #pragma unroll
                for (int h = 0; h < H; ++h) pacc[h] += attL[h * N + j0 + j] * zc;
            }
        } else {
            const unsigned short* zp =
                (const unsigned short*)z + (i * N + j0) * CZ + c;
            for (int j = 0; j < 128; ++j) {
                float zc = bfu(zp[j * CZ]);
                #pragma unroll
                for (int h = 0; h < H; ++h) pacc[h] += attL[h * N + j0 + j] * zc;
            }
        }
        __syncthreads();   // U free (zT dead since Phase A)
        #pragma unroll
        for (int h = 0; h < H; ++h) U[quarter * (H * CZ) + h * CZ + c] = pacc[h];
    }
    __syncthreads();
    for (int idx = t; idx < H * CZ; idx += 512)
        cat[i * 2112 + 576 + idx] =
            U[idx] + U[1536 + idx] + U[3072 + idx] + U[4608 + idx];
}

// ---------------------------------------------------------------------------
// K4: final_gemm — out = cat @ Wout + bout, barrier-free split-bf16 MFMA.
// A = cat (f32 workspace, no dtype branch), B = pre-split WoutT_h/l.
// Tile 32x64, 4 waves, grid (16,16), no LDS, no K-loop barriers.
// ---------------------------------------------------------------------------
__global__ void final_gemm(const float* cat, const unsigned short* BTh,
                           const unsigned short* BTl, const void* bout,
                           void* out, const void* s)
{
    __shared__ int flag;
    int t = threadIdx.x;               // 256
    int bn = blockIdx.x;               // 16 col tiles of 64
    int bm = blockIdx.y;               // 16 row tiles of 32
    if (t == 0) flag = sniff_f32((const unsigned short*)s);
    __syncthreads();
    int f32 = flag;

    int w  = t >> 6, l = t & 63;
    int wm = w >> 1, wn = w & 1;
    int lr = l & 15, lq = l >> 4;

    int arow = bm * 32 + wm * 16 + lr;
    int bcol = bn * 64 + wn * 32 + lr;
    const unsigned short* bh = BTh + bcol * KC;
    const unsigned short* bl = BTl + bcol * KC;
    const float* ap0 = cat + arow * KC;

    f32x4 acc0 = {0.f, 0.f, 0.f, 0.f};
    f32x4 acc1 = {0.f, 0.f, 0.f, 0.f};

    #pragma unroll 2
    for (int kt = 0; kt < KC / 32; ++kt) {
        int kk = kt * 32 + lq * 8;
        u16x8 ah, al;
        const float* ap = ap0 + kk;
        #pragma unroll
        for (int e = 0; e < 8; ++e) {
            unsigned int pe = split_bf16(ap[e]);
            ah[e] = (unsigned short)pe; al[e] = (unsigned short)(pe >> 16);
        }
        bf16x8 b0h = *(const bf16x8*)(bh + kk);
        bf16x8 b0l = *(const bf16x8*)(bl + kk);
        bf16x8 b1h = *(const bf16x8*)(bh + 16 * KC + kk);
        bf16x8 b1l = *(const bf16x8*)(bl + 16 * KC + kk);
        bf16x8 a_h = *(bf16x8*)&ah;
        bf16x8 a_l = *(bf16x8*)&al;
        acc0 = __builtin_amdgcn_mfma_f32_16x16x32_bf16(a_h, b0h, acc0, 0, 0, 0);
        acc0 = __builtin_amdgcn_mfma_f32_16x16x32_bf16(a_h, b0l, acc0, 0, 0, 0);
        acc0 = __builtin_amdgcn_mfma_f32_16x16x32_bf16(a_l, b0h, acc0, 0, 0, 0);
        acc1 = __builtin_amdgcn_mfma_f32_16x16x32_bf16(a_h, b1h, acc1, 0, 0, 0);
        acc1 = __builtin_amdgcn_mfma_f32_16x16x32_bf16(a_h, b1l, acc1, 0, 0, 0);
        acc1 = __builtin_amdgcn_mfma_f32_16x16x32_bf16(a_l, b1h, acc1, 0, 0, 0);
    }

    int col0 = bn * 64 + wn * 32 + lr;
    int row0 = bm * 32 + wm * 16 + lq * 4;
    float bv0 = ld(bout, col0, f32);
    float bv1 = ld(bout, col0 + 16, f32);
    if (f32) {
        float* o = (float*)out;
        #pragma unroll
        for (int r = 0; r < 4; ++r) {
            o[(row0 + r) * CS + col0]      = acc0[r] + bv0;
            o[(row0 + r) * CS + col0 + 16] = acc1[r] + bv1;
        }
    } else {
        __hip_bfloat16* o = (__hip_bfloat16*)out;
        #pragma unroll
        for (int r = 0; r < 4; ++r) {
            o[(row0 + r) * CS + col0]      = __float2bfloat16(acc0[r] + bv0);
            o[(row0 + r) * CS + col0 + 16] = __float2bfloat16(acc1[r] + bv1);
        }
    }
}

extern "C" void kernel_launch(void* const* d_in, const int* in_sizes, int n_in,
                              void* d_out, int out_size, void* d_ws, size_t ws_size,
                              hipStream_t stream)
{
    const void* s      = d_in[0];
    const void* z      = d_in[1];
    const void* rot    = d_in[2];
    const void* trans  = d_in[3];
    const void* mask   = d_in[4];
    const void* Wq     = d_in[5];  const void* bq   = d_in[6];
    const void* Wkv    = d_in[7];  const void* bkv  = d_in[8];
    const void* Wqp    = d_in[9];  const void* bqp  = d_in[10];
    const void* Wkvp   = d_in[11]; const void* bkvp = d_in[12];
    const void* Wb     = d_in[13]; const void* bb   = d_in[14];
    const void* head_w = d_in[15];
    const void* Wout   = d_in[16]; const void* bout = d_in[17];

    float* w    = (float*)d_ws;
    float* q    = w;                    // 512*192
    float* kT   = q   + 98304;          // [192][512] transposed
    float* v    = kT  + 98304;          // 512*192
    float* qp   = v   + 98304;          // 512*144
    float* kpT  = qp  + 73728;          // [144][512] transposed
    float* vp   = kpT + 73728;          // 512*288
    float* cat  = vp  + 147456;         // 512*2112
    float* rawP = cat;                  // 512*1152, aliases cat (dead before attn)
    // bf16 split-weight arrays after the float region (16B-aligned offsets)
    unsigned short* WcTh = (unsigned short*)(cat + 512 * 2112);
    unsigned short* WcTl = WcTh + 1152 * 1024;
    unsigned short* WoTh = WcTl + 1152 * 1024;
    unsigned short* WoTl = WoTh + 1024 * 2112;
    // total ws use: 6.68 MB floats + 13.4 MB bf16 = 20.1 MB
    (void)ws_size; (void)in_sizes; (void)n_in; (void)out_size;

    prep_w    <<<3264, 256, 0, stream>>>(Wq, Wkv, Wqp, Wkvp, Wout, s,
                                         WcTh, WcTl, WoTh, WoTl);
    proj_gemm <<<dim3(18, 16), 256, 0, stream>>>(s, WcTh, WcTl, rawP);
    proj_post <<<512, 576, 0, stream>>>(rawP, bq, bkv, bqp, bkvp, rot, trans, s,
                                        q, kT, v, qp, kpT, vp);
    attn_fused<<<512, 512, 0, stream>>>(q, kT, v, qp, kpT, vp, z, Wb, bb, head_w, mask,
                                        rot, trans, s, cat);
    final_gemm<<<dim3(16, 16), 256, 0, stream>>>(cat, WoTh, WoTl, bout, d_out, s);
}